// Round 1
// baseline (3005.484 us; speedup 1.0000x reference)
//
#include <hip/hip_runtime.h>

#define NN 100000
#define NE 1600000
// IN_C = HID_C = 64, OUT_C = 16

// ---------------- degree / norm ----------------
__global__ void deg_kernel(const int* __restrict__ dst, int* __restrict__ deg) {
    int e = blockIdx.x * blockDim.x + threadIdx.x;
    if (e < NE) atomicAdd(&deg[dst[e]], 1);
}

__global__ void dinv_kernel(const int* __restrict__ deg, float* __restrict__ dinv) {
    int i = blockIdx.x * blockDim.x + threadIdx.x;
    if (i < NN) dinv[i] = rsqrtf((float)(deg[i] + 1));   // +1 self-loop
}

// ---------------- hh = (in @ W[64x64]) * dinv[row] ----------------
__global__ void gemm64_kernel(const float* __restrict__ in, const float* __restrict__ W,
                              const float* __restrict__ dinv, float* __restrict__ out) {
    __shared__ float Ws[64][64];   // 16 KB
    __shared__ float xs[4][64];
    int t = threadIdx.x;
    #pragma unroll
    for (int k = 0; k < 16; ++k)
        ((float*)Ws)[k * 256 + t] = W[k * 256 + t];
    int nl = t >> 6;          // node within block (wave id)
    int c  = t & 63;          // output channel
    int node = blockIdx.x * 4 + nl;
    xs[nl][c] = in[node * 64 + c];
    __syncthreads();
    float acc = 0.f;
    #pragma unroll
    for (int k = 0; k < 64; ++k)
        acc = fmaf(xs[nl][k], Ws[k][c], acc);
    out[node * 64 + c] = acc * dinv[node];
}

// ---------------- edge scatter: acc[dst] += hh[src] ----------------
__global__ void scatter_kernel(const int* __restrict__ src, const int* __restrict__ dst,
                               const float* __restrict__ hh, float* __restrict__ acc) {
    int tid = blockIdx.x * blockDim.x + threadIdx.x;
    int e = tid >> 4;          // 16 threads per edge
    int q = tid & 15;          // 4-channel group
    if (e < NE) {
        int s = src[e], d = dst[e];
        float4 v = *(const float4*)(hh + s * 64 + q * 4);
        float* a = acc + d * 64 + q * 4;
        atomicAdd(a + 0, v.x);
        atomicAdd(a + 1, v.y);
        atomicAdd(a + 2, v.z);
        atomicAdd(a + 3, v.w);
    }
}

// ---------------- out = relu(dinv*(acc + hh) + b), in-place over acc ----------------
__global__ void finish_kernel(const float* __restrict__ accb, const float* __restrict__ hh,
                              const float* __restrict__ dinv, const float* __restrict__ b,
                              float* __restrict__ out) {
    int tid = blockIdx.x * blockDim.x + threadIdx.x;
    if (tid < NN * 16) {
        int i = tid >> 4, q = tid & 15;
        float di = dinv[i];
        float4 a  = *(const float4*)(accb + i * 64 + q * 4);
        float4 h  = *(const float4*)(hh   + i * 64 + q * 4);
        float4 bb = *(const float4*)(b + q * 4);
        float4 r;
        r.x = fmaxf(fmaf(di, a.x + h.x, bb.x), 0.f);
        r.y = fmaxf(fmaf(di, a.y + h.y, bb.y), 0.f);
        r.z = fmaxf(fmaf(di, a.z + h.z, bb.z), 0.f);
        r.w = fmaxf(fmaf(di, a.w + h.w, bb.w), 0.f);
        *(float4*)(out + i * 64 + q * 4) = r;
    }
}

// ---------------- logits = h @ Wfc + bfc ; log_softmax over 16 ----------------
__global__ void final_kernel(const float* __restrict__ h, const float* __restrict__ Wfc,
                             const float* __restrict__ bfc, float* __restrict__ out) {
    __shared__ float Ws[64][16];   // 4 KB
    __shared__ float hs[16][68];   // padded to break bank aliasing
    int t = threadIdx.x;
    #pragma unroll
    for (int k = 0; k < 4; ++k)
        ((float*)Ws)[k * 256 + t] = Wfc[k * 256 + t];
    int node0 = blockIdx.x * 16;
    #pragma unroll
    for (int k = 0; k < 4; ++k) {
        int idx = k * 256 + t;
        int r = idx >> 6, cc = idx & 63;
        hs[r][cc] = h[(node0 + r) * 64 + cc];
    }
    __syncthreads();
    int nl = t >> 4;          // node within block
    int c  = t & 15;          // output channel
    float acc = bfc[c];
    #pragma unroll
    for (int k = 0; k < 64; ++k)
        acc = fmaf(hs[nl][k], Ws[k][c], acc);
    // log-softmax across the 16-lane group
    float m = acc;
    #pragma unroll
    for (int off = 8; off; off >>= 1)
        m = fmaxf(m, __shfl_xor(m, off, 16));
    float ex = __expf(acc - m);
    float s = ex;
    #pragma unroll
    for (int off = 8; off; off >>= 1)
        s += __shfl_xor(s, off, 16);
    out[(node0 + nl) * 16 + c] = acc - m - __logf(s);
}

extern "C" void kernel_launch(void* const* d_in, const int* in_sizes, int n_in,
                              void* d_out, int out_size, void* d_ws, size_t ws_size,
                              hipStream_t stream) {
    const float* x   = (const float*)d_in[0];
    const int*   ei  = (const int*)d_in[1];     // [2, E] int32 per harness convention
    const float* W1  = (const float*)d_in[2];
    const float* b1  = (const float*)d_in[3];
    const float* W2  = (const float*)d_in[4];
    const float* b2  = (const float*)d_in[5];
    const float* Wfc = (const float*)d_in[6];
    const float* bfc = (const float*)d_in[7];
    float* out = (float*)d_out;

    char* ws = (char*)d_ws;
    int*   deg  = (int*)ws;                                   // N ints      (400 KB)
    float* dinv = (float*)(ws + 400000);                      // N floats    (400 KB)
    float* bufA = (float*)(ws + 800000);                      // N*64 floats (25.6 MB)
    float* bufB = (float*)(ws + 800000 + 25600000);           // N*64 floats (25.6 MB)

    const int* src = ei;        // edge_index[0]
    const int* dst = ei + NE;   // edge_index[1]

    hipMemsetAsync(deg, 0, NN * sizeof(int), stream);
    deg_kernel<<<(NE + 255) / 256, 256, 0, stream>>>(dst, deg);
    dinv_kernel<<<(NN + 255) / 256, 256, 0, stream>>>(deg, dinv);

    // ---- layer 1 ----
    gemm64_kernel<<<NN / 4, 256, 0, stream>>>(x, W1, dinv, bufA);
    hipMemsetAsync(bufB, 0, NN * 64 * sizeof(float), stream);
    scatter_kernel<<<(NE * 16) / 256, 256, 0, stream>>>(src, dst, bufA, bufB);
    finish_kernel<<<(NN * 16 + 255) / 256, 256, 0, stream>>>(bufB, bufA, dinv, b1, bufB);

    // ---- layer 2 ----
    gemm64_kernel<<<NN / 4, 256, 0, stream>>>(bufB, W2, dinv, bufA);
    hipMemsetAsync(bufB, 0, NN * 64 * sizeof(float), stream);
    scatter_kernel<<<(NE * 16) / 256, 256, 0, stream>>>(src, dst, bufA, bufB);
    finish_kernel<<<(NN * 16 + 255) / 256, 256, 0, stream>>>(bufB, bufA, dinv, b2, bufB);

    // ---- FC + log_softmax ----
    final_kernel<<<NN / 16, 256, 0, stream>>>(bufB, Wfc, bfc, out);
}

// Round 2
// 547.659 us; speedup vs baseline: 5.4879x; 5.4879x over previous
//
#include <hip/hip_runtime.h>

#define NN 100000
#define NE 1600000
// IN_C = HID_C = 64, OUT_C = 16

// ---------------- degree histogram ----------------
__global__ void deg_kernel(const int* __restrict__ dst, int* __restrict__ deg) {
    int e = blockIdx.x * blockDim.x + threadIdx.x;
    if (e < NE) atomicAdd(&deg[dst[e]], 1);
}

__global__ void dinv_kernel(const int* __restrict__ deg, float* __restrict__ dinv) {
    int i = blockIdx.x * blockDim.x + threadIdx.x;
    if (i < NN) dinv[i] = rsqrtf((float)(deg[i] + 1));   // +1 self-loop
}

// ---------------- prefix scan (3-kernel, 1024 el/block) ----------------
// scan1: per-block exclusive scan of deg into cursor; block total -> bsum[b]
__global__ void scan1_kernel(const int* __restrict__ deg, int* __restrict__ cursor,
                             int* __restrict__ bsum) {
    __shared__ int sd[256];
    int t = threadIdx.x;
    int base = blockIdx.x * 1024 + t * 4;
    int d0 = 0, d1 = 0, d2 = 0, d3 = 0;
    if (base + 0 < NN) d0 = deg[base + 0];
    if (base + 1 < NN) d1 = deg[base + 1];
    if (base + 2 < NN) d2 = deg[base + 2];
    if (base + 3 < NN) d3 = deg[base + 3];
    int my = d0 + d1 + d2 + d3;
    sd[t] = my;
    __syncthreads();
    #pragma unroll
    for (int off = 1; off < 256; off <<= 1) {
        int v = (t >= off) ? sd[t - off] : 0;
        __syncthreads();
        sd[t] += v;
        __syncthreads();
    }
    int excl = sd[t] - my;            // exclusive prefix of this thread's chunk
    if (base + 0 < NN) cursor[base + 0] = excl;
    if (base + 1 < NN) cursor[base + 1] = excl + d0;
    if (base + 2 < NN) cursor[base + 2] = excl + d0 + d1;
    if (base + 3 < NN) cursor[base + 3] = excl + d0 + d1 + d2;
    if (t == 255) bsum[blockIdx.x] = sd[255];
}

// scan2: single block, exclusive scan of 98 block sums (padded to 128)
__global__ void scan2_kernel(int* __restrict__ bsum, int* __restrict__ boff, int nb) {
    __shared__ int sd[128];
    int t = threadIdx.x;
    int my = (t < nb) ? bsum[t] : 0;
    sd[t] = my;
    __syncthreads();
    #pragma unroll
    for (int off = 1; off < 128; off <<= 1) {
        int v = (t >= off) ? sd[t - off] : 0;
        __syncthreads();
        sd[t] += v;
        __syncthreads();
    }
    if (t < nb) boff[t] = sd[t] - my;   // exclusive
}

// scan3: add block offsets
__global__ void scan3_kernel(int* __restrict__ cursor, const int* __restrict__ boff) {
    int i = blockIdx.x * blockDim.x + threadIdx.x;
    if (i < NN) cursor[i] += boff[i >> 10];
}

// ---------------- CSR fill: cursor[i] ends at row_start[i]+deg[i] ----------------
__global__ void fill_kernel(const int* __restrict__ src, const int* __restrict__ dst,
                            int* __restrict__ cursor, int* __restrict__ sorted_src) {
    int e = blockIdx.x * blockDim.x + threadIdx.x;
    if (e < NE) {
        int pos = atomicAdd(&cursor[dst[e]], 1);
        sorted_src[pos] = src[e];
    }
}

// ---------------- hh = (in @ W[64x64]) * dinv[row] ----------------
__global__ void gemm64_kernel(const float* __restrict__ in, const float* __restrict__ W,
                              const float* __restrict__ dinv, float* __restrict__ out) {
    __shared__ float Ws[64][64];   // 16 KB
    __shared__ float xs[4][64];
    int t = threadIdx.x;
    #pragma unroll
    for (int k = 0; k < 16; ++k)
        ((float*)Ws)[k * 256 + t] = W[k * 256 + t];
    int nl = t >> 6;          // node within block (wave id)
    int c  = t & 63;          // output channel
    int node = blockIdx.x * 4 + nl;
    xs[nl][c] = in[node * 64 + c];
    __syncthreads();
    float acc = 0.f;
    #pragma unroll
    for (int k = 0; k < 64; ++k)
        acc = fmaf(xs[nl][k], Ws[k][c], acc);
    out[node * 64 + c] = acc * dinv[node];
}

// ---------------- CSR gather + fused finish ----------------
// out[i] = relu(dinv[i] * (sum_{j in N(i)} hh[j] + hh[i]) + b)
__global__ void aggregate_kernel(const int* __restrict__ cursor,  // == row_start + deg
                                 const int* __restrict__ deg,
                                 const int* __restrict__ sorted_src,
                                 const float* __restrict__ hh,
                                 const float* __restrict__ dinv,
                                 const float* __restrict__ b,
                                 float* __restrict__ out) {
    int tid = blockIdx.x * blockDim.x + threadIdx.x;
    int node = tid >> 4;
    int q = tid & 15;
    if (node >= NN) return;
    int cnt = deg[node];
    int end = cursor[node];          // row_start + cnt
    int e = end - cnt;               // row_start
    float4 acc = *(const float4*)(hh + node * 64 + q * 4);   // self-loop term
    for (; e + 1 < end; e += 2) {
        int s1 = sorted_src[e];
        int s2 = sorted_src[e + 1];
        float4 v1 = *(const float4*)(hh + s1 * 64 + q * 4);
        float4 v2 = *(const float4*)(hh + s2 * 64 + q * 4);
        acc.x += v1.x; acc.y += v1.y; acc.z += v1.z; acc.w += v1.w;
        acc.x += v2.x; acc.y += v2.y; acc.z += v2.z; acc.w += v2.w;
    }
    if (e < end) {
        int s1 = sorted_src[e];
        float4 v1 = *(const float4*)(hh + s1 * 64 + q * 4);
        acc.x += v1.x; acc.y += v1.y; acc.z += v1.z; acc.w += v1.w;
    }
    float di = dinv[node];
    float4 bb = *(const float4*)(b + q * 4);
    float4 r;
    r.x = fmaxf(fmaf(di, acc.x, bb.x), 0.f);
    r.y = fmaxf(fmaf(di, acc.y, bb.y), 0.f);
    r.z = fmaxf(fmaf(di, acc.z, bb.z), 0.f);
    r.w = fmaxf(fmaf(di, acc.w, bb.w), 0.f);
    *(float4*)(out + node * 64 + q * 4) = r;
}

// ---------------- logits = h @ Wfc + bfc ; log_softmax over 16 ----------------
__global__ void final_kernel(const float* __restrict__ h, const float* __restrict__ Wfc,
                             const float* __restrict__ bfc, float* __restrict__ out) {
    __shared__ float Ws[64][16];   // 4 KB
    __shared__ float hs[16][68];   // padded to break bank aliasing
    int t = threadIdx.x;
    #pragma unroll
    for (int k = 0; k < 4; ++k)
        ((float*)Ws)[k * 256 + t] = Wfc[k * 256 + t];
    int node0 = blockIdx.x * 16;
    #pragma unroll
    for (int k = 0; k < 4; ++k) {
        int idx = k * 256 + t;
        int r = idx >> 6, cc = idx & 63;
        hs[r][cc] = h[(node0 + r) * 64 + cc];
    }
    __syncthreads();
    int nl = t >> 4;          // node within block
    int c  = t & 15;          // output channel
    float acc = bfc[c];
    #pragma unroll
    for (int k = 0; k < 64; ++k)
        acc = fmaf(hs[nl][k], Ws[k][c], acc);
    // log-softmax across the 16-lane group
    float m = acc;
    #pragma unroll
    for (int off = 8; off; off >>= 1)
        m = fmaxf(m, __shfl_xor(m, off, 16));
    float ex = __expf(acc - m);
    float s = ex;
    #pragma unroll
    for (int off = 8; off; off >>= 1)
        s += __shfl_xor(s, off, 16);
    out[(node0 + nl) * 16 + c] = acc - m - __logf(s);
}

extern "C" void kernel_launch(void* const* d_in, const int* in_sizes, int n_in,
                              void* d_out, int out_size, void* d_ws, size_t ws_size,
                              hipStream_t stream) {
    const float* x   = (const float*)d_in[0];
    const int*   ei  = (const int*)d_in[1];     // [2, E] int32
    const float* W1  = (const float*)d_in[2];
    const float* b1  = (const float*)d_in[3];
    const float* W2  = (const float*)d_in[4];
    const float* b2  = (const float*)d_in[5];
    const float* Wfc = (const float*)d_in[6];
    const float* bfc = (const float*)d_in[7];
    float* out = (float*)d_out;

    char* ws = (char*)d_ws;
    int*   deg    = (int*)(ws + 0);            // 400 KB
    float* dinv   = (float*)(ws + 524288);     // 400 KB
    int*   cursor = (int*)(ws + 1048576);      // 400 KB
    int*   bsum   = (int*)(ws + 1572864);      // 512 B
    int*   boff   = (int*)(ws + 1574912);      // 512 B
    int*   srt    = (int*)(ws + 2097152);      // 6.4 MB sorted src indices
    float* bufA   = (float*)(ws + 9000000);    // 25.6 MB (hh)
    float* bufB   = (float*)(ws + 34600000);   // 25.6 MB

    const int* src = ei;        // edge_index[0]
    const int* dst = ei + NE;   // edge_index[1]

    const int NB_SCAN = (NN + 1023) / 1024;    // 98

    // ---- CSR build + norm (once, reused by both layers) ----
    hipMemsetAsync(deg, 0, NN * sizeof(int), stream);
    deg_kernel<<<(NE + 255) / 256, 256, 0, stream>>>(dst, deg);
    dinv_kernel<<<(NN + 255) / 256, 256, 0, stream>>>(deg, dinv);
    scan1_kernel<<<NB_SCAN, 256, 0, stream>>>(deg, cursor, bsum);
    scan2_kernel<<<1, 128, 0, stream>>>(bsum, boff, NB_SCAN);
    scan3_kernel<<<(NN + 255) / 256, 256, 0, stream>>>(cursor, boff);
    fill_kernel<<<(NE + 255) / 256, 256, 0, stream>>>(src, dst, cursor, srt);
    // now cursor[i] == row_start[i] + deg[i]

    // ---- layer 1 ----
    gemm64_kernel<<<NN / 4, 256, 0, stream>>>(x, W1, dinv, bufA);
    aggregate_kernel<<<(NN * 16 + 255) / 256, 256, 0, stream>>>(cursor, deg, srt, bufA, dinv, b1, bufB);

    // ---- layer 2 ----
    gemm64_kernel<<<NN / 4, 256, 0, stream>>>(bufB, W2, dinv, bufA);
    aggregate_kernel<<<(NN * 16 + 255) / 256, 256, 0, stream>>>(cursor, deg, srt, bufA, dinv, b2, bufB);

    // ---- FC + log_softmax ----
    final_kernel<<<NN / 16, 256, 0, stream>>>(bufB, Wfc, bfc, out);
}

// Round 3
// 495.700 us; speedup vs baseline: 6.0631x; 1.1048x over previous
//
#include <hip/hip_runtime.h>

#define NN 100000
#define NE 1600000
#define NPB 128                       // nodes per coarse bucket (node>>7)
#define NBUCK ((NN + NPB - 1) / NPB)  // 782
#define EPB 16384                     // edges per block in bucket_scatter
// IN_C = HID_C = 64, OUT_C = 16

// ---------------- degree histogram (int4 loads) ----------------
__global__ void deg_kernel(const int4* __restrict__ dst4, int* __restrict__ deg) {
    int i = blockIdx.x * blockDim.x + threadIdx.x;
    if (i < NE / 4) {
        int4 d = dst4[i];
        atomicAdd(&deg[d.x], 1);
        atomicAdd(&deg[d.y], 1);
        atomicAdd(&deg[d.z], 1);
        atomicAdd(&deg[d.w], 1);
    }
}

__global__ void dinv_kernel(const int* __restrict__ deg, float* __restrict__ dinv) {
    int i = blockIdx.x * blockDim.x + threadIdx.x;
    if (i < NN) dinv[i] = rsqrtf((float)(deg[i] + 1));   // +1 self-loop
}

// ---------------- prefix scan (3-kernel, 1024 el/block) ----------------
__global__ void scan1_kernel(const int* __restrict__ deg, int* __restrict__ row_start,
                             int* __restrict__ bsum) {
    __shared__ int sd[256];
    int t = threadIdx.x;
    int base = blockIdx.x * 1024 + t * 4;
    int d0 = 0, d1 = 0, d2 = 0, d3 = 0;
    if (base + 0 < NN) d0 = deg[base + 0];
    if (base + 1 < NN) d1 = deg[base + 1];
    if (base + 2 < NN) d2 = deg[base + 2];
    if (base + 3 < NN) d3 = deg[base + 3];
    int my = d0 + d1 + d2 + d3;
    sd[t] = my;
    __syncthreads();
    #pragma unroll
    for (int off = 1; off < 256; off <<= 1) {
        int v = (t >= off) ? sd[t - off] : 0;
        __syncthreads();
        sd[t] += v;
        __syncthreads();
    }
    int excl = sd[t] - my;
    if (base + 0 < NN) row_start[base + 0] = excl;
    if (base + 1 < NN) row_start[base + 1] = excl + d0;
    if (base + 2 < NN) row_start[base + 2] = excl + d0 + d1;
    if (base + 3 < NN) row_start[base + 3] = excl + d0 + d1 + d2;
    if (t == 255) bsum[blockIdx.x] = sd[255];
}

__global__ void scan2_kernel(int* __restrict__ bsum, int* __restrict__ boff, int nb) {
    __shared__ int sd[128];
    int t = threadIdx.x;
    int my = (t < nb) ? bsum[t] : 0;
    sd[t] = my;
    __syncthreads();
    #pragma unroll
    for (int off = 1; off < 128; off <<= 1) {
        int v = (t >= off) ? sd[t - off] : 0;
        __syncthreads();
        sd[t] += v;
        __syncthreads();
    }
    if (t < nb) boff[t] = sd[t] - my;
}

__global__ void scan3_kernel(int* __restrict__ row_start, const int* __restrict__ boff) {
    int i = blockIdx.x * blockDim.x + threadIdx.x;
    if (i < NN) row_start[i] += boff[i >> 10];
}

// ---------------- bucket cursor init: bcur[b] = row_start[first node of b] ----
__global__ void init_bcur_kernel(const int* __restrict__ row_start, int* __restrict__ bcur) {
    int b = blockIdx.x * blockDim.x + threadIdx.x;
    if (b < NBUCK) bcur[b] = row_start[b * NPB];
}

// ---------------- F2: block-aggregated coarse bucket scatter ----------------
// Each block: LDS histogram over NBUCK buckets, ONE global atomic per touched
// bucket to allocate a contiguous chunk, then stream (src,dst) pairs in.
__global__ void bucket_scatter_kernel(const int* __restrict__ src, const int* __restrict__ dst,
                                      int* __restrict__ bcur, int2* __restrict__ pairs) {
    __shared__ int hist[NBUCK];
    __shared__ int base[NBUCK];
    int t = threadIdx.x;
    for (int i = t; i < NBUCK; i += 256) hist[i] = 0;
    __syncthreads();
    int start = blockIdx.x * EPB;
    int end = min(start + EPB, NE);
    for (int e = start + t; e < end; e += 256)
        atomicAdd(&hist[dst[e] >> 7], 1);
    __syncthreads();
    for (int i = t; i < NBUCK; i += 256) {
        int c = hist[i];
        base[i] = (c > 0) ? atomicAdd(&bcur[i], c) : 0;
        hist[i] = 0;
    }
    __syncthreads();
    for (int e = start + t; e < end; e += 256) {
        int d = dst[e];
        int b = d >> 7;
        int pos = base[b] + atomicAdd(&hist[b], 1);
        pairs[pos] = make_int2(src[e], d);
    }
}

// ---------------- F3: exact CSR placement within each bucket ----------------
__global__ void place_kernel(const int* __restrict__ row_start,
                             const int2* __restrict__ pairs,
                             int* __restrict__ sorted_src) {
    __shared__ int lcnt[NPB];
    __shared__ int rs[NPB];
    int b = blockIdx.x;
    int t = threadIdx.x;
    int node0 = b * NPB;
    if (t < NPB) {
        int n = node0 + t;
        lcnt[t] = 0;
        rs[t] = (n < NN) ? row_start[n] : NE;
    }
    __syncthreads();
    int rs_b = row_start[node0];
    int next0 = node0 + NPB;
    int rs_e = (next0 < NN) ? row_start[next0] : NE;
    for (int pos = rs_b + t; pos < rs_e; pos += 256) {
        int2 p = pairs[pos];
        int loc = p.y - node0;
        int off = atomicAdd(&lcnt[loc], 1);
        sorted_src[rs[loc] + off] = p.x;
    }
}

// ---------------- hh = (in @ W[64x64]) * dinv[row] ----------------
__global__ void gemm64_kernel(const float* __restrict__ in, const float* __restrict__ W,
                              const float* __restrict__ dinv, float* __restrict__ out) {
    __shared__ float Ws[64][64];
    __shared__ float xs[4][64];
    int t = threadIdx.x;
    #pragma unroll
    for (int k = 0; k < 16; ++k)
        ((float*)Ws)[k * 256 + t] = W[k * 256 + t];
    int nl = t >> 6;
    int c  = t & 63;
    int node = blockIdx.x * 4 + nl;
    xs[nl][c] = in[node * 64 + c];
    __syncthreads();
    float acc = 0.f;
    #pragma unroll
    for (int k = 0; k < 64; ++k)
        acc = fmaf(xs[nl][k], Ws[k][c], acc);
    out[node * 64 + c] = acc * dinv[node];
}

// ---------------- CSR gather + fused finish ----------------
__global__ void aggregate_kernel(const int* __restrict__ row_start,
                                 const int* __restrict__ deg,
                                 const int* __restrict__ sorted_src,
                                 const float* __restrict__ hh,
                                 const float* __restrict__ dinv,
                                 const float* __restrict__ b,
                                 float* __restrict__ out) {
    int tid = blockIdx.x * blockDim.x + threadIdx.x;
    int node = tid >> 4;
    int q = tid & 15;
    if (node >= NN) return;
    int e = row_start[node];
    int end = e + deg[node];
    float4 acc = *(const float4*)(hh + node * 64 + q * 4);   // self-loop term
    for (; e + 1 < end; e += 2) {
        int s1 = sorted_src[e];
        int s2 = sorted_src[e + 1];
        float4 v1 = *(const float4*)(hh + s1 * 64 + q * 4);
        float4 v2 = *(const float4*)(hh + s2 * 64 + q * 4);
        acc.x += v1.x; acc.y += v1.y; acc.z += v1.z; acc.w += v1.w;
        acc.x += v2.x; acc.y += v2.y; acc.z += v2.z; acc.w += v2.w;
    }
    if (e < end) {
        int s1 = sorted_src[e];
        float4 v1 = *(const float4*)(hh + s1 * 64 + q * 4);
        acc.x += v1.x; acc.y += v1.y; acc.z += v1.z; acc.w += v1.w;
    }
    float di = dinv[node];
    float4 bb = *(const float4*)(b + q * 4);
    float4 r;
    r.x = fmaxf(fmaf(di, acc.x, bb.x), 0.f);
    r.y = fmaxf(fmaf(di, acc.y, bb.y), 0.f);
    r.z = fmaxf(fmaf(di, acc.z, bb.z), 0.f);
    r.w = fmaxf(fmaf(di, acc.w, bb.w), 0.f);
    *(float4*)(out + node * 64 + q * 4) = r;
}

// ---------------- logits = h @ Wfc + bfc ; log_softmax over 16 ----------------
__global__ void final_kernel(const float* __restrict__ h, const float* __restrict__ Wfc,
                             const float* __restrict__ bfc, float* __restrict__ out) {
    __shared__ float Ws[64][16];
    __shared__ float hs[16][68];
    int t = threadIdx.x;
    #pragma unroll
    for (int k = 0; k < 4; ++k)
        ((float*)Ws)[k * 256 + t] = Wfc[k * 256 + t];
    int node0 = blockIdx.x * 16;
    #pragma unroll
    for (int k = 0; k < 4; ++k) {
        int idx = k * 256 + t;
        int r = idx >> 6, cc = idx & 63;
        hs[r][cc] = h[(node0 + r) * 64 + cc];
    }
    __syncthreads();
    int nl = t >> 4;
    int c  = t & 15;
    float acc = bfc[c];
    #pragma unroll
    for (int k = 0; k < 64; ++k)
        acc = fmaf(hs[nl][k], Ws[k][c], acc);
    float m = acc;
    #pragma unroll
    for (int off = 8; off; off >>= 1)
        m = fmaxf(m, __shfl_xor(m, off, 16));
    float ex = __expf(acc - m);
    float s = ex;
    #pragma unroll
    for (int off = 8; off; off >>= 1)
        s += __shfl_xor(s, off, 16);
    out[(node0 + nl) * 16 + c] = acc - m - __logf(s);
}

extern "C" void kernel_launch(void* const* d_in, const int* in_sizes, int n_in,
                              void* d_out, int out_size, void* d_ws, size_t ws_size,
                              hipStream_t stream) {
    const float* x   = (const float*)d_in[0];
    const int*   ei  = (const int*)d_in[1];     // [2, E] int32
    const float* W1  = (const float*)d_in[2];
    const float* b1  = (const float*)d_in[3];
    const float* W2  = (const float*)d_in[4];
    const float* b2  = (const float*)d_in[5];
    const float* Wfc = (const float*)d_in[6];
    const float* bfc = (const float*)d_in[7];
    float* out = (float*)d_out;

    char* ws = (char*)d_ws;
    int*   deg       = (int*)(ws + 0);            // 400 KB
    float* dinv      = (float*)(ws + 524288);     // 400 KB
    int*   row_start = (int*)(ws + 1048576);      // 400 KB
    int*   bsum      = (int*)(ws + 1572864);      // 392 B
    int*   boff      = (int*)(ws + 1574912);      // 392 B
    int*   bcur      = (int*)(ws + 1576960);      // 3128 B
    int*   srt       = (int*)(ws + 2097152);      // 6.4 MB    (ends 8.5 MB)
    float* bufA      = (float*)(ws + 8500000);    // 25.6 MB   (ends 34.1 MB)
    float* bufB      = (float*)(ws + 34100000);   // 25.6 MB   (ends 59.7 MB)
    int2*  pairs     = (int2*)(ws + 34100000);    // 12.8 MB — aliases bufB; dead before
                                                  // bufB is first written (stream-ordered)

    const int* src = ei;        // edge_index[0]
    const int* dst = ei + NE;   // edge_index[1]

    const int NB_SCAN = (NN + 1023) / 1024;       // 98
    const int NB_F2   = (NE + EPB - 1) / EPB;     // 98

    // ---- CSR build + norm (reused by both layers) ----
    hipMemsetAsync(deg, 0, NN * sizeof(int), stream);
    deg_kernel<<<(NE / 4 + 255) / 256, 256, 0, stream>>>((const int4*)dst, deg);
    dinv_kernel<<<(NN + 255) / 256, 256, 0, stream>>>(deg, dinv);
    scan1_kernel<<<NB_SCAN, 256, 0, stream>>>(deg, row_start, bsum);
    scan2_kernel<<<1, 128, 0, stream>>>(bsum, boff, NB_SCAN);
    scan3_kernel<<<(NN + 255) / 256, 256, 0, stream>>>(row_start, boff);
    init_bcur_kernel<<<(NBUCK + 255) / 256, 256, 0, stream>>>(row_start, bcur);
    bucket_scatter_kernel<<<NB_F2, 256, 0, stream>>>(src, dst, bcur, pairs);
    place_kernel<<<NBUCK, 256, 0, stream>>>(row_start, pairs, srt);

    // ---- layer 1 ----
    gemm64_kernel<<<NN / 4, 256, 0, stream>>>(x, W1, dinv, bufA);
    aggregate_kernel<<<(NN * 16 + 255) / 256, 256, 0, stream>>>(row_start, deg, srt, bufA, dinv, b1, bufB);

    // ---- layer 2 ----
    gemm64_kernel<<<NN / 4, 256, 0, stream>>>(bufB, W2, dinv, bufA);
    aggregate_kernel<<<(NN * 16 + 255) / 256, 256, 0, stream>>>(row_start, deg, srt, bufA, dinv, b2, bufB);

    // ---- FC + log_softmax ----
    final_kernel<<<NN / 16, 256, 0, stream>>>(bufB, Wfc, bfc, out);
}

// Round 4
// 433.258 us; speedup vs baseline: 6.9369x; 1.1441x over previous
//
#include <hip/hip_runtime.h>

#define NN 100000
#define NE 1600000
#define NPB 128                       // nodes per coarse bucket (node>>7)
#define NBUCK ((NN + NPB - 1) / NPB)  // 782
#define EPB 16384                     // edges per block in bucket_scatter
// IN_C = HID_C = 64, OUT_C = 16

// fp32 -> bf16 (round-to-nearest-even), returns low 16 bits
__device__ inline unsigned f2bf(float f) {
    unsigned u = __float_as_uint(f);
    return (u + 0x7fffu + ((u >> 16) & 1u)) >> 16;
}

// 4 packed bf16 (uint2) -> float4
__device__ inline float4 bf4_to_f4(uint2 u) {
    float4 r;
    r.x = __uint_as_float(u.x << 16);
    r.y = __uint_as_float(u.x & 0xffff0000u);
    r.z = __uint_as_float(u.y << 16);
    r.w = __uint_as_float(u.y & 0xffff0000u);
    return r;
}

// ---------------- degree histogram (int4 loads) ----------------
__global__ void deg_kernel(const int4* __restrict__ dst4, int* __restrict__ deg) {
    int i = blockIdx.x * blockDim.x + threadIdx.x;
    if (i < NE / 4) {
        int4 d = dst4[i];
        atomicAdd(&deg[d.x], 1);
        atomicAdd(&deg[d.y], 1);
        atomicAdd(&deg[d.z], 1);
        atomicAdd(&deg[d.w], 1);
    }
}

__global__ void dinv_kernel(const int* __restrict__ deg, float* __restrict__ dinv) {
    int i = blockIdx.x * blockDim.x + threadIdx.x;
    if (i < NN) dinv[i] = rsqrtf((float)(deg[i] + 1));   // +1 self-loop
}

// ---------------- prefix scan (3-kernel, 1024 el/block) ----------------
__global__ void scan1_kernel(const int* __restrict__ deg, int* __restrict__ row_start,
                             int* __restrict__ bsum) {
    __shared__ int sd[256];
    int t = threadIdx.x;
    int base = blockIdx.x * 1024 + t * 4;
    int d0 = 0, d1 = 0, d2 = 0, d3 = 0;
    if (base + 0 < NN) d0 = deg[base + 0];
    if (base + 1 < NN) d1 = deg[base + 1];
    if (base + 2 < NN) d2 = deg[base + 2];
    if (base + 3 < NN) d3 = deg[base + 3];
    int my = d0 + d1 + d2 + d3;
    sd[t] = my;
    __syncthreads();
    #pragma unroll
    for (int off = 1; off < 256; off <<= 1) {
        int v = (t >= off) ? sd[t - off] : 0;
        __syncthreads();
        sd[t] += v;
        __syncthreads();
    }
    int excl = sd[t] - my;
    if (base + 0 < NN) row_start[base + 0] = excl;
    if (base + 1 < NN) row_start[base + 1] = excl + d0;
    if (base + 2 < NN) row_start[base + 2] = excl + d0 + d1;
    if (base + 3 < NN) row_start[base + 3] = excl + d0 + d1 + d2;
    if (t == 255) bsum[blockIdx.x] = sd[255];
}

__global__ void scan2_kernel(int* __restrict__ bsum, int* __restrict__ boff, int nb) {
    __shared__ int sd[128];
    int t = threadIdx.x;
    int my = (t < nb) ? bsum[t] : 0;
    sd[t] = my;
    __syncthreads();
    #pragma unroll
    for (int off = 1; off < 128; off <<= 1) {
        int v = (t >= off) ? sd[t - off] : 0;
        __syncthreads();
        sd[t] += v;
        __syncthreads();
    }
    if (t < nb) boff[t] = sd[t] - my;
}

__global__ void scan3_kernel(int* __restrict__ row_start, const int* __restrict__ boff) {
    int i = blockIdx.x * blockDim.x + threadIdx.x;
    if (i < NN) row_start[i] += boff[i >> 10];
}

__global__ void init_bcur_kernel(const int* __restrict__ row_start, int* __restrict__ bcur) {
    int b = blockIdx.x * blockDim.x + threadIdx.x;
    if (b < NBUCK) bcur[b] = row_start[b * NPB];
}

// ---------------- F2: block-aggregated coarse bucket scatter ----------------
__global__ void bucket_scatter_kernel(const int* __restrict__ src, const int* __restrict__ dst,
                                      int* __restrict__ bcur, int2* __restrict__ pairs) {
    __shared__ int hist[NBUCK];
    __shared__ int base[NBUCK];
    int t = threadIdx.x;
    for (int i = t; i < NBUCK; i += 256) hist[i] = 0;
    __syncthreads();
    int start = blockIdx.x * EPB;
    int end = min(start + EPB, NE);
    for (int e = start + t; e < end; e += 256)
        atomicAdd(&hist[dst[e] >> 7], 1);
    __syncthreads();
    for (int i = t; i < NBUCK; i += 256) {
        int c = hist[i];
        base[i] = (c > 0) ? atomicAdd(&bcur[i], c) : 0;
        hist[i] = 0;
    }
    __syncthreads();
    for (int e = start + t; e < end; e += 256) {
        int d = dst[e];
        int b = d >> 7;
        int pos = base[b] + atomicAdd(&hist[b], 1);
        pairs[pos] = make_int2(src[e], d);
    }
}

// ---------------- F3: exact CSR placement within each bucket ----------------
__global__ void place_kernel(const int* __restrict__ row_start,
                             const int2* __restrict__ pairs,
                             int* __restrict__ sorted_src) {
    __shared__ int lcnt[NPB];
    __shared__ int rs[NPB];
    int b = blockIdx.x;
    int t = threadIdx.x;
    int node0 = b * NPB;
    if (t < NPB) {
        int n = node0 + t;
        lcnt[t] = 0;
        rs[t] = (n < NN) ? row_start[n] : NE;
    }
    __syncthreads();
    int rs_b = row_start[node0];
    int next0 = node0 + NPB;
    int rs_e = (next0 < NN) ? row_start[next0] : NE;
    for (int pos = rs_b + t; pos < rs_e; pos += 256) {
        int2 p = pairs[pos];
        int loc = p.y - node0;
        int off = atomicAdd(&lcnt[loc], 1);
        sorted_src[rs[loc] + off] = p.x;
    }
}

// ---------------- hh(bf16) = (in @ W[64x64]) * dinv[row] ----------------
__global__ void gemm64_kernel(const float* __restrict__ in, const float* __restrict__ W,
                              const float* __restrict__ dinv,
                              unsigned* __restrict__ out /* bf16 pairs, N*32 */) {
    __shared__ float Ws[64][64];
    __shared__ float xs[4][64];
    int t = threadIdx.x;
    #pragma unroll
    for (int k = 0; k < 16; ++k)
        ((float*)Ws)[k * 256 + t] = W[k * 256 + t];
    int nl = t >> 6;
    int c  = t & 63;
    int node = blockIdx.x * 4 + nl;
    xs[nl][c] = in[node * 64 + c];
    __syncthreads();
    float acc = 0.f;
    #pragma unroll
    for (int k = 0; k < 64; ++k)
        acc = fmaf(xs[nl][k], Ws[k][c], acc);
    float v = acc * dinv[node];
    float p = __shfl_xor(v, 1);       // partner channel (c^1), same node
    if ((c & 1) == 0) {
        unsigned lo = f2bf(v), hi = f2bf(p);
        out[node * 32 + (c >> 1)] = lo | (hi << 16);
    }
}

// ---------------- CSR gather (bf16 rows) + fused finish ----------------
// out[i] = relu(dinv[i] * (sum_{j in N(i)} hh[j] + hh[i]) + b)
__global__ void aggregate_kernel(const int* __restrict__ row_start,
                                 const int* __restrict__ deg,
                                 const int* __restrict__ sorted_src,
                                 const uint2* __restrict__ hb,   // bf16 rows, 16 uint2/row
                                 const float* __restrict__ dinv,
                                 const float* __restrict__ b,
                                 float* __restrict__ out) {
    int tid = blockIdx.x * blockDim.x + threadIdx.x;
    int node = tid >> 4;
    int q = tid & 15;
    if (node >= NN) return;
    int e = row_start[node];
    int end = e + deg[node];
    float4 acc = bf4_to_f4(hb[node * 16 + q]);   // self-loop term
    while (e < end) {
        int take = min(end - e, 16);
        int sidx = (q < take) ? sorted_src[e + q] : 0;   // one coalesced load / 16 edges
        int j = 0;
        for (; j + 4 <= take; j += 4) {
            int s0 = __shfl(sidx, j + 0, 16);
            int s1 = __shfl(sidx, j + 1, 16);
            int s2 = __shfl(sidx, j + 2, 16);
            int s3 = __shfl(sidx, j + 3, 16);
            uint2 u0 = hb[s0 * 16 + q];
            uint2 u1 = hb[s1 * 16 + q];
            uint2 u2 = hb[s2 * 16 + q];
            uint2 u3 = hb[s3 * 16 + q];
            float4 v0 = bf4_to_f4(u0), v1 = bf4_to_f4(u1);
            float4 v2 = bf4_to_f4(u2), v3 = bf4_to_f4(u3);
            acc.x += v0.x + v1.x + v2.x + v3.x;
            acc.y += v0.y + v1.y + v2.y + v3.y;
            acc.z += v0.z + v1.z + v2.z + v3.z;
            acc.w += v0.w + v1.w + v2.w + v3.w;
        }
        for (; j < take; ++j) {
            int s0 = __shfl(sidx, j, 16);
            float4 v0 = bf4_to_f4(hb[s0 * 16 + q]);
            acc.x += v0.x; acc.y += v0.y; acc.z += v0.z; acc.w += v0.w;
        }
        e += take;
    }
    float di = dinv[node];
    float4 bb = *(const float4*)(b + q * 4);
    float4 r;
    r.x = fmaxf(fmaf(di, acc.x, bb.x), 0.f);
    r.y = fmaxf(fmaf(di, acc.y, bb.y), 0.f);
    r.z = fmaxf(fmaf(di, acc.z, bb.z), 0.f);
    r.w = fmaxf(fmaf(di, acc.w, bb.w), 0.f);
    *(float4*)(out + node * 64 + q * 4) = r;
}

// ---------------- logits = h @ Wfc + bfc ; log_softmax over 16 ----------------
__global__ void final_kernel(const float* __restrict__ h, const float* __restrict__ Wfc,
                             const float* __restrict__ bfc, float* __restrict__ out) {
    __shared__ float Ws[64][16];
    __shared__ float hs[16][68];
    int t = threadIdx.x;
    #pragma unroll
    for (int k = 0; k < 4; ++k)
        ((float*)Ws)[k * 256 + t] = Wfc[k * 256 + t];
    int node0 = blockIdx.x * 16;
    #pragma unroll
    for (int k = 0; k < 4; ++k) {
        int idx = k * 256 + t;
        int r = idx >> 6, cc = idx & 63;
        hs[r][cc] = h[(node0 + r) * 64 + cc];
    }
    __syncthreads();
    int nl = t >> 4;
    int c  = t & 15;
    float acc = bfc[c];
    #pragma unroll
    for (int k = 0; k < 64; ++k)
        acc = fmaf(hs[nl][k], Ws[k][c], acc);
    float m = acc;
    #pragma unroll
    for (int off = 8; off; off >>= 1)
        m = fmaxf(m, __shfl_xor(m, off, 16));
    float ex = __expf(acc - m);
    float s = ex;
    #pragma unroll
    for (int off = 8; off; off >>= 1)
        s += __shfl_xor(s, off, 16);
    out[(node0 + nl) * 16 + c] = acc - m - __logf(s);
}

extern "C" void kernel_launch(void* const* d_in, const int* in_sizes, int n_in,
                              void* d_out, int out_size, void* d_ws, size_t ws_size,
                              hipStream_t stream) {
    const float* x   = (const float*)d_in[0];
    const int*   ei  = (const int*)d_in[1];     // [2, E] int32
    const float* W1  = (const float*)d_in[2];
    const float* b1  = (const float*)d_in[3];
    const float* W2  = (const float*)d_in[4];
    const float* b2  = (const float*)d_in[5];
    const float* Wfc = (const float*)d_in[6];
    const float* bfc = (const float*)d_in[7];
    float* out = (float*)d_out;

    char* ws = (char*)d_ws;
    int*      deg       = (int*)(ws + 0);            // 400 KB
    float*    dinv      = (float*)(ws + 524288);     // 400 KB
    int*      row_start = (int*)(ws + 1048576);      // 400 KB
    int*      bsum      = (int*)(ws + 1572864);      // 392 B
    int*      boff      = (int*)(ws + 1574912);      // 392 B
    int*      bcur      = (int*)(ws + 1576960);      // 3128 B
    int*      srt       = (int*)(ws + 2097152);      // 6.4 MB   (ends 8.5 MB)
    unsigned* bufA      = (unsigned*)(ws + 8500000); // 12.8 MB bf16 hh (ends 21.3 MB)
    float*    bufB      = (float*)(ws + 21300000);   // 25.6 MB fp32    (ends 46.9 MB)
    int2*     pairs     = (int2*)(ws + 21300000);    // 12.8 MB — aliases bufB; dead
                                                     // before bufB's first write

    const int* src = ei;        // edge_index[0]
    const int* dst = ei + NE;   // edge_index[1]

    const int NB_SCAN = (NN + 1023) / 1024;       // 98
    const int NB_F2   = (NE + EPB - 1) / EPB;     // 98

    // ---- CSR build + norm (reused by both layers) ----
    hipMemsetAsync(deg, 0, NN * sizeof(int), stream);
    deg_kernel<<<(NE / 4 + 255) / 256, 256, 0, stream>>>((const int4*)dst, deg);
    dinv_kernel<<<(NN + 255) / 256, 256, 0, stream>>>(deg, dinv);
    scan1_kernel<<<NB_SCAN, 256, 0, stream>>>(deg, row_start, bsum);
    scan2_kernel<<<1, 128, 0, stream>>>(bsum, boff, NB_SCAN);
    scan3_kernel<<<(NN + 255) / 256, 256, 0, stream>>>(row_start, boff);
    init_bcur_kernel<<<(NBUCK + 255) / 256, 256, 0, stream>>>(row_start, bcur);
    bucket_scatter_kernel<<<NB_F2, 256, 0, stream>>>(src, dst, bcur, pairs);
    place_kernel<<<NBUCK, 256, 0, stream>>>(row_start, pairs, srt);

    // ---- layer 1 ----
    gemm64_kernel<<<NN / 4, 256, 0, stream>>>(x, W1, dinv, bufA);
    aggregate_kernel<<<(NN * 16 + 255) / 256, 256, 0, stream>>>(row_start, deg, srt, (const uint2*)bufA, dinv, b1, bufB);

    // ---- layer 2 ----
    gemm64_kernel<<<NN / 4, 256, 0, stream>>>(bufB, W2, dinv, bufA);
    aggregate_kernel<<<(NN * 16 + 255) / 256, 256, 0, stream>>>(row_start, deg, srt, (const uint2*)bufA, dinv, b2, bufB);

    // ---- FC + log_softmax ----
    final_kernel<<<NN / 16, 256, 0, stream>>>(bufB, Wfc, bfc, out);
}

// Round 5
// 306.947 us; speedup vs baseline: 9.7916x; 1.4115x over previous
//
#include <hip/hip_runtime.h>

#define NN 100000
#define NE 1600000
#define NPB 128                       // nodes per coarse bucket (node>>7)
#define NBUCK ((NN + NPB - 1) / NPB)  // 782
#define NSB 512                       // scatter blocks
#define ESB (NE / NSB)                // 3125 edges per scatter block
// IN_C = HID_C = 64, OUT_C = 16

// fp32 -> bf16 (round-to-nearest-even), returns low 16 bits
__device__ inline unsigned f2bf(float f) {
    unsigned u = __float_as_uint(f);
    return (u + 0x7fffu + ((u >> 16) & 1u)) >> 16;
}

// 4 packed bf16 (uint2) -> float4
__device__ inline float4 bf4_to_f4(uint2 u) {
    float4 r;
    r.x = __uint_as_float(u.x << 16);
    r.y = __uint_as_float(u.x & 0xffff0000u);
    r.z = __uint_as_float(u.y << 16);
    r.w = __uint_as_float(u.y & 0xffff0000u);
    return r;
}

// ---------------- S0: per-block coarse bucket histogram ----------------
__global__ void hist_kernel(const int* __restrict__ dst, int* __restrict__ histT) {
    __shared__ int lhist[NBUCK];
    int t = threadIdx.x;
    for (int i = t; i < NBUCK; i += 256) lhist[i] = 0;
    __syncthreads();
    int start = blockIdx.x * ESB, end = start + ESB;
    for (int e = start + t; e < end; e += 256)
        atomicAdd(&lhist[dst[e] >> 7], 1);
    __syncthreads();
    for (int i = t; i < NBUCK; i += 256)
        histT[i * NSB + blockIdx.x] = lhist[i];   // transposed: bucket-major
}

// ---------------- S1: per-bucket scan of 512 block counts ----------------
__global__ void colscan_kernel(const int* __restrict__ histT, int* __restrict__ baseT,
                               int* __restrict__ btot) {
    __shared__ int sd[256];
    int k = blockIdx.x, t = threadIdx.x;
    const int* col = histT + k * NSB;
    int a0 = col[2 * t], a1 = col[2 * t + 1];
    int my = a0 + a1;
    sd[t] = my;
    __syncthreads();
    #pragma unroll
    for (int off = 1; off < 256; off <<= 1) {
        int v = (t >= off) ? sd[t - off] : 0;
        __syncthreads();
        sd[t] += v;
        __syncthreads();
    }
    int excl = sd[t] - my;
    baseT[k * NSB + 2 * t]     = excl;
    baseT[k * NSB + 2 * t + 1] = excl + a0;
    if (t == 255) btot[k] = sd[255];
}

// ---------------- S2: scan bucket totals -> bucket_start[NBUCK+1] ----------------
__global__ void bscan_kernel(const int* __restrict__ btot, int* __restrict__ bucket_start) {
    __shared__ int sd[256];
    int t = threadIdx.x;
    int base = t * 4;
    int d0 = (base + 0 < NBUCK) ? btot[base + 0] : 0;
    int d1 = (base + 1 < NBUCK) ? btot[base + 1] : 0;
    int d2 = (base + 2 < NBUCK) ? btot[base + 2] : 0;
    int d3 = (base + 3 < NBUCK) ? btot[base + 3] : 0;
    int my = d0 + d1 + d2 + d3;
    sd[t] = my;
    __syncthreads();
    #pragma unroll
    for (int off = 1; off < 256; off <<= 1) {
        int v = (t >= off) ? sd[t - off] : 0;
        __syncthreads();
        sd[t] += v;
        __syncthreads();
    }
    int excl = sd[t] - my;
    if (base + 0 < NBUCK) bucket_start[base + 0] = excl;
    if (base + 1 < NBUCK) bucket_start[base + 1] = excl + d0;
    if (base + 2 < NBUCK) bucket_start[base + 2] = excl + d0 + d1;
    if (base + 3 < NBUCK) bucket_start[base + 3] = excl + d0 + d1 + d2;
    if (t == 255) bucket_start[NBUCK] = sd[255];   // == NE
}

// ---------------- S3: stable bucket scatter (no global atomics) ----------------
__global__ void scatter2_kernel(const int* __restrict__ src, const int* __restrict__ dst,
                                const int* __restrict__ baseT,
                                const int* __restrict__ bucket_start,
                                int2* __restrict__ pairs) {
    __shared__ int lcur[NBUCK];
    int t = threadIdx.x, b = blockIdx.x;
    for (int i = t; i < NBUCK; i += 256)
        lcur[i] = bucket_start[i] + baseT[i * NSB + b];
    __syncthreads();
    int start = b * ESB, end = start + ESB;
    for (int e = start + t; e < end; e += 256) {
        int d = dst[e];
        int pos = atomicAdd(&lcur[d >> 7], 1);
        pairs[pos] = make_int2(src[e], d);
    }
}

// ---------------- S4: per-bucket deg/dinv/row_start + exact CSR placement ----
__global__ void place_deg_kernel(const int* __restrict__ bucket_start,
                                 const int2* __restrict__ pairs,
                                 int* __restrict__ deg, float* __restrict__ dinv,
                                 int* __restrict__ row_start,
                                 int* __restrict__ sorted_src) {
    __shared__ int lcnt[NPB];
    __shared__ int loff[NPB];
    __shared__ int lpos[NPB];
    __shared__ int sd[NPB];
    int k = blockIdx.x, t = threadIdx.x;
    int node0 = k * NPB;
    if (t < NPB) { lcnt[t] = 0; lpos[t] = 0; }
    __syncthreads();
    int bs = bucket_start[k], be = bucket_start[k + 1];
    for (int pos = bs + t; pos < be; pos += 256)
        atomicAdd(&lcnt[pairs[pos].y - node0], 1);
    __syncthreads();
    int my = (t < NPB) ? lcnt[t] : 0;
    if (t < NPB) sd[t] = my;
    __syncthreads();
    #pragma unroll
    for (int off = 1; off < NPB; off <<= 1) {
        int v = (t < NPB && t >= off) ? sd[t - off] : 0;
        __syncthreads();
        if (t < NPB) sd[t] += v;
        __syncthreads();
    }
    if (t < NPB) {
        int excl = sd[t] - my;
        loff[t] = excl;
        int n = node0 + t;
        if (n < NN) {
            deg[n] = my;
            dinv[n] = rsqrtf((float)(my + 1));
            row_start[n] = bs + excl;
        }
    }
    __syncthreads();
    for (int pos = bs + t; pos < be; pos += 256) {
        int2 p = pairs[pos];
        int loc = p.y - node0;
        int off = atomicAdd(&lpos[loc], 1);
        sorted_src[bs + loff[loc] + off] = p.x;
    }
}

// ---------------- hh(bf16) = (in @ W[64x64]) * dinv[row] ----------------
__global__ void gemm64_kernel(const float* __restrict__ in, const float* __restrict__ W,
                              const float* __restrict__ dinv,
                              unsigned* __restrict__ out /* bf16 pairs, N*32 */) {
    __shared__ float Ws[64][64];
    __shared__ float xs[4][64];
    int t = threadIdx.x;
    #pragma unroll
    for (int k = 0; k < 16; ++k)
        ((float*)Ws)[k * 256 + t] = W[k * 256 + t];
    int nl = t >> 6;
    int c  = t & 63;
    int node = blockIdx.x * 4 + nl;
    xs[nl][c] = in[node * 64 + c];
    __syncthreads();
    float acc = 0.f;
    #pragma unroll
    for (int k = 0; k < 64; ++k)
        acc = fmaf(xs[nl][k], Ws[k][c], acc);
    float v = acc * dinv[node];
    float p = __shfl_xor(v, 1);       // partner channel (c^1), same node
    if ((c & 1) == 0) {
        unsigned lo = f2bf(v), hi = f2bf(p);
        out[node * 32 + (c >> 1)] = lo | (hi << 16);
    }
}

// ---------------- CSR gather (bf16 rows) + fused finish ----------------
__global__ void aggregate_kernel(const int* __restrict__ row_start,
                                 const int* __restrict__ deg,
                                 const int* __restrict__ sorted_src,
                                 const uint2* __restrict__ hb,   // bf16 rows, 16 uint2/row
                                 const float* __restrict__ dinv,
                                 const float* __restrict__ b,
                                 float* __restrict__ out) {
    int tid = blockIdx.x * blockDim.x + threadIdx.x;
    int node = tid >> 4;
    int q = tid & 15;
    if (node >= NN) return;
    int e = row_start[node];
    int end = e + deg[node];
    float4 acc = bf4_to_f4(hb[node * 16 + q]);   // self-loop term
    while (e < end) {
        int take = min(end - e, 16);
        int sidx = (q < take) ? sorted_src[e + q] : 0;   // one coalesced load / 16 edges
        int j = 0;
        for (; j + 4 <= take; j += 4) {
            int s0 = __shfl(sidx, j + 0, 16);
            int s1 = __shfl(sidx, j + 1, 16);
            int s2 = __shfl(sidx, j + 2, 16);
            int s3 = __shfl(sidx, j + 3, 16);
            uint2 u0 = hb[s0 * 16 + q];
            uint2 u1 = hb[s1 * 16 + q];
            uint2 u2 = hb[s2 * 16 + q];
            uint2 u3 = hb[s3 * 16 + q];
            float4 v0 = bf4_to_f4(u0), v1 = bf4_to_f4(u1);
            float4 v2 = bf4_to_f4(u2), v3 = bf4_to_f4(u3);
            acc.x += v0.x + v1.x + v2.x + v3.x;
            acc.y += v0.y + v1.y + v2.y + v3.y;
            acc.z += v0.z + v1.z + v2.z + v3.z;
            acc.w += v0.w + v1.w + v2.w + v3.w;
        }
        for (; j < take; ++j) {
            int s0 = __shfl(sidx, j, 16);
            float4 v0 = bf4_to_f4(hb[s0 * 16 + q]);
            acc.x += v0.x; acc.y += v0.y; acc.z += v0.z; acc.w += v0.w;
        }
        e += take;
    }
    float di = dinv[node];
    float4 bb = *(const float4*)(b + q * 4);
    float4 r;
    r.x = fmaxf(fmaf(di, acc.x, bb.x), 0.f);
    r.y = fmaxf(fmaf(di, acc.y, bb.y), 0.f);
    r.z = fmaxf(fmaf(di, acc.z, bb.z), 0.f);
    r.w = fmaxf(fmaf(di, acc.w, bb.w), 0.f);
    *(float4*)(out + node * 64 + q * 4) = r;
}

// ---------------- logits = h @ Wfc + bfc ; log_softmax over 16 ----------------
__global__ void final_kernel(const float* __restrict__ h, const float* __restrict__ Wfc,
                             const float* __restrict__ bfc, float* __restrict__ out) {
    __shared__ float Ws[64][16];
    __shared__ float hs[16][68];
    int t = threadIdx.x;
    #pragma unroll
    for (int k = 0; k < 4; ++k)
        ((float*)Ws)[k * 256 + t] = Wfc[k * 256 + t];
    int node0 = blockIdx.x * 16;
    #pragma unroll
    for (int k = 0; k < 4; ++k) {
        int idx = k * 256 + t;
        int r = idx >> 6, cc = idx & 63;
        hs[r][cc] = h[(node0 + r) * 64 + cc];
    }
    __syncthreads();
    int nl = t >> 4;
    int c  = t & 15;
    float acc = bfc[c];
    #pragma unroll
    for (int k = 0; k < 64; ++k)
        acc = fmaf(hs[nl][k], Ws[k][c], acc);
    float m = acc;
    #pragma unroll
    for (int off = 8; off; off >>= 1)
        m = fmaxf(m, __shfl_xor(m, off, 16));
    float ex = __expf(acc - m);
    float s = ex;
    #pragma unroll
    for (int off = 8; off; off >>= 1)
        s += __shfl_xor(s, off, 16);
    out[(node0 + nl) * 16 + c] = acc - m - __logf(s);
}

extern "C" void kernel_launch(void* const* d_in, const int* in_sizes, int n_in,
                              void* d_out, int out_size, void* d_ws, size_t ws_size,
                              hipStream_t stream) {
    const float* x   = (const float*)d_in[0];
    const int*   ei  = (const int*)d_in[1];     // [2, E] int32
    const float* W1  = (const float*)d_in[2];
    const float* b1  = (const float*)d_in[3];
    const float* W2  = (const float*)d_in[4];
    const float* b2  = (const float*)d_in[5];
    const float* Wfc = (const float*)d_in[6];
    const float* bfc = (const float*)d_in[7];
    float* out = (float*)d_out;

    char* ws = (char*)d_ws;
    int*      deg          = (int*)(ws + 0);            // 400 KB
    float*    dinv         = (float*)(ws + 524288);     // 400 KB
    int*      row_start    = (int*)(ws + 1048576);      // 400 KB
    int*      btot         = (int*)(ws + 1572864);      // 3128 B
    int*      bucket_start = (int*)(ws + 1576960);      // 3132 B
    int*      histT        = (int*)(ws + 1581056);      // 1.6 MB (ends 3.18 MB)
    int*      baseT        = (int*)(ws + 3182592);      // 1.6 MB (ends 4.78 MB)
    int*      srt          = (int*)(ws + 4784128);      // 6.4 MB (ends 11.18 MB)
    unsigned* bufA         = (unsigned*)(ws + 11184128);// 12.8 MB bf16 hh (ends 23.98 MB)
    float*    bufB         = (float*)(ws + 23984128);   // 25.6 MB fp32 (ends 49.58 MB)
    int2*     pairs        = (int2*)(ws + 23984128);    // 12.8 MB — aliases bufB; dead
                                                        // before bufB's first write

    const int* src = ei;        // edge_index[0]
    const int* dst = ei + NE;   // edge_index[1]

    // ---- CSR build (deterministic two-level counting sort; no global atomics) ----
    hist_kernel<<<NSB, 256, 0, stream>>>(dst, histT);
    colscan_kernel<<<NBUCK, 256, 0, stream>>>(histT, baseT, btot);
    bscan_kernel<<<1, 256, 0, stream>>>(btot, bucket_start);
    scatter2_kernel<<<NSB, 256, 0, stream>>>(src, dst, baseT, bucket_start, pairs);
    place_deg_kernel<<<NBUCK, 256, 0, stream>>>(bucket_start, pairs, deg, dinv, row_start, srt);

    // ---- layer 1 ----
    gemm64_kernel<<<NN / 4, 256, 0, stream>>>(x, W1, dinv, bufA);
    aggregate_kernel<<<(NN * 16 + 255) / 256, 256, 0, stream>>>(row_start, deg, srt, (const uint2*)bufA, dinv, b1, bufB);

    // ---- layer 2 ----
    gemm64_kernel<<<NN / 4, 256, 0, stream>>>(bufB, W2, dinv, bufA);
    aggregate_kernel<<<(NN * 16 + 255) / 256, 256, 0, stream>>>(row_start, deg, srt, (const uint2*)bufA, dinv, b2, bufB);

    // ---- FC + log_softmax ----
    final_kernel<<<NN / 16, 256, 0, stream>>>(bufB, Wfc, bfc, out);
}

// Round 6
// 241.830 us; speedup vs baseline: 12.4281x; 1.2693x over previous
//
#include <hip/hip_runtime.h>

#define NN 100000
#define NE 1600000
#define NPB 128                       // nodes per coarse bucket (node>>7)
#define NBUCK ((NN + NPB - 1) / NPB)  // 782
#define NSB 512                       // scatter blocks
#define ESB (NE / NSB)                // 3125 edges per scatter block
// IN_C = HID_C = 64, OUT_C = 16

typedef __bf16 v8bf __attribute__((ext_vector_type(8)));
typedef float  v4f  __attribute__((ext_vector_type(4)));

union Frag { v8bf v; uint4 u; unsigned short s[8]; };

// fp32 -> bf16 (round-to-nearest-even), returns low 16 bits
__device__ inline unsigned f2bf(float f) {
    unsigned u = __float_as_uint(f);
    return (u + 0x7fffu + ((u >> 16) & 1u)) >> 16;
}

// 4 packed bf16 (uint2) -> float4
__device__ inline float4 bf4_to_f4(uint2 u) {
    float4 r;
    r.x = __uint_as_float(u.x << 16);
    r.y = __uint_as_float(u.x & 0xffff0000u);
    r.z = __uint_as_float(u.y << 16);
    r.w = __uint_as_float(u.y & 0xffff0000u);
    return r;
}

// ---------------- S0: per-block coarse bucket histogram ----------------
__global__ void hist_kernel(const int* __restrict__ dst, int* __restrict__ histT) {
    __shared__ int lhist[NBUCK];
    int t = threadIdx.x;
    for (int i = t; i < NBUCK; i += 256) lhist[i] = 0;
    __syncthreads();
    int start = blockIdx.x * ESB, end = start + ESB;
    for (int e = start + t; e < end; e += 256)
        atomicAdd(&lhist[dst[e] >> 7], 1);
    __syncthreads();
    for (int i = t; i < NBUCK; i += 256)
        histT[i * NSB + blockIdx.x] = lhist[i];   // transposed: bucket-major
}

// ---------------- S1: per-bucket scan of 512 block counts ----------------
__global__ void colscan_kernel(const int* __restrict__ histT, int* __restrict__ baseT,
                               int* __restrict__ btot) {
    __shared__ int sd[256];
    int k = blockIdx.x, t = threadIdx.x;
    const int* col = histT + k * NSB;
    int a0 = col[2 * t], a1 = col[2 * t + 1];
    int my = a0 + a1;
    sd[t] = my;
    __syncthreads();
    #pragma unroll
    for (int off = 1; off < 256; off <<= 1) {
        int v = (t >= off) ? sd[t - off] : 0;
        __syncthreads();
        sd[t] += v;
        __syncthreads();
    }
    int excl = sd[t] - my;
    baseT[k * NSB + 2 * t]     = excl;
    baseT[k * NSB + 2 * t + 1] = excl + a0;
    if (t == 255) btot[k] = sd[255];
}

// ---------------- S2: scan bucket totals -> bucket_start[NBUCK+1] ----------------
__global__ void bscan_kernel(const int* __restrict__ btot, int* __restrict__ bucket_start) {
    __shared__ int sd[256];
    int t = threadIdx.x;
    int base = t * 4;
    int d0 = (base + 0 < NBUCK) ? btot[base + 0] : 0;
    int d1 = (base + 1 < NBUCK) ? btot[base + 1] : 0;
    int d2 = (base + 2 < NBUCK) ? btot[base + 2] : 0;
    int d3 = (base + 3 < NBUCK) ? btot[base + 3] : 0;
    int my = d0 + d1 + d2 + d3;
    sd[t] = my;
    __syncthreads();
    #pragma unroll
    for (int off = 1; off < 256; off <<= 1) {
        int v = (t >= off) ? sd[t - off] : 0;
        __syncthreads();
        sd[t] += v;
        __syncthreads();
    }
    int excl = sd[t] - my;
    if (base + 0 < NBUCK) bucket_start[base + 0] = excl;
    if (base + 1 < NBUCK) bucket_start[base + 1] = excl + d0;
    if (base + 2 < NBUCK) bucket_start[base + 2] = excl + d0 + d1;
    if (base + 3 < NBUCK) bucket_start[base + 3] = excl + d0 + d1 + d2;
    if (t == 255) bucket_start[NBUCK] = sd[255];   // == NE
}

// ---------------- S3: stable bucket scatter (no global atomics) ----------------
__global__ void scatter2_kernel(const int* __restrict__ src, const int* __restrict__ dst,
                                const int* __restrict__ baseT,
                                const int* __restrict__ bucket_start,
                                int2* __restrict__ pairs) {
    __shared__ int lcur[NBUCK];
    int t = threadIdx.x, b = blockIdx.x;
    for (int i = t; i < NBUCK; i += 256)
        lcur[i] = bucket_start[i] + baseT[i * NSB + b];
    __syncthreads();
    int start = b * ESB, end = start + ESB;
    for (int e = start + t; e < end; e += 256) {
        int d = dst[e];
        int pos = atomicAdd(&lcur[d >> 7], 1);
        pairs[pos] = make_int2(src[e], d);
    }
}

// ---------------- S4: per-bucket deg/dinv/row_start + exact CSR placement ----
__global__ void place_deg_kernel(const int* __restrict__ bucket_start,
                                 const int2* __restrict__ pairs,
                                 int* __restrict__ deg, float* __restrict__ dinv,
                                 int* __restrict__ row_start,
                                 int* __restrict__ sorted_src) {
    __shared__ int lcnt[NPB];
    __shared__ int loff[NPB];
    __shared__ int lpos[NPB];
    __shared__ int sd[NPB];
    int k = blockIdx.x, t = threadIdx.x;
    int node0 = k * NPB;
    if (t < NPB) { lcnt[t] = 0; lpos[t] = 0; }
    __syncthreads();
    int bs = bucket_start[k], be = bucket_start[k + 1];
    for (int pos = bs + t; pos < be; pos += 256)
        atomicAdd(&lcnt[pairs[pos].y - node0], 1);
    __syncthreads();
    int my = (t < NPB) ? lcnt[t] : 0;
    if (t < NPB) sd[t] = my;
    __syncthreads();
    #pragma unroll
    for (int off = 1; off < NPB; off <<= 1) {
        int v = (t < NPB && t >= off) ? sd[t - off] : 0;
        __syncthreads();
        if (t < NPB) sd[t] += v;
        __syncthreads();
    }
    if (t < NPB) {
        int excl = sd[t] - my;
        loff[t] = excl;
        int n = node0 + t;
        if (n < NN) {
            deg[n] = my;
            dinv[n] = rsqrtf((float)(my + 1));
            row_start[n] = bs + excl;
        }
    }
    __syncthreads();
    for (int pos = bs + t; pos < be; pos += 256) {
        int2 p = pairs[pos];
        int loc = p.y - node0;
        int off = atomicAdd(&lpos[loc], 1);
        sorted_src[bs + loff[loc] + off] = p.x;
    }
}

// ---------------- W pack: fp32 64x64 -> bf16 B-fragments ----------------
// frag f = (cs*4 + q), lane n, elem j:  Wp[(f*16+n)*8+j] = bf16(W[32*s+8*q+j][16*c+n])
// where cs = c*2+s. Total 4096 ushort = 8 KB.
__global__ void wpack_kernel(const float* __restrict__ W1, const float* __restrict__ W2,
                             unsigned short* __restrict__ Wp1, unsigned short* __restrict__ Wp2) {
    const float* W = blockIdx.x ? W2 : W1;
    unsigned short* Wp = blockIdx.x ? Wp2 : Wp1;
    int t = threadIdx.x;
    for (int idx = t; idx < 4096; idx += 256) {
        int j = idx & 7;
        int n = (idx >> 3) & 15;
        int f = idx >> 7;          // 0..31
        int q = f & 3;
        int s = (f >> 2) & 1;
        int c = f >> 3;
        int k = 32 * s + 8 * q + j;
        int col = 16 * c + n;
        Wp[idx] = (unsigned short)f2bf(W[k * 64 + col]);
    }
}

// ---------------- hh(bf16) = (in @ W) * dinv[row]  via MFMA ----------------
// Wave = 16-node x 64-channel tile; 8x mfma_f32_16x16x32_bf16.
__global__ void gemm_mfma_kernel(const float* __restrict__ in,
                                 const unsigned short* __restrict__ Wp,
                                 const float* __restrict__ dinv,
                                 unsigned* __restrict__ out /* bf16 pairs, N*32 */) {
    int lane = threadIdx.x & 63;
    int wv = threadIdx.x >> 6;
    int node0 = blockIdx.x * 64 + wv * 16;
    int m = lane & 15, quad = lane >> 4;
    int node = node0 + m;
    int lnode = (node < NN) ? node : NN - 1;    // clamp for tail block

    // A fragments: A[m=lane&15][k=quad*8+j], one per K-step
    Frag a[2];
    const float* xr = in + lnode * 64 + quad * 8;
    #pragma unroll
    for (int s = 0; s < 2; ++s) {
        float4 f0 = *(const float4*)(xr + s * 32);
        float4 f1 = *(const float4*)(xr + s * 32 + 4);
        a[s].s[0] = (unsigned short)f2bf(f0.x);
        a[s].s[1] = (unsigned short)f2bf(f0.y);
        a[s].s[2] = (unsigned short)f2bf(f0.z);
        a[s].s[3] = (unsigned short)f2bf(f0.w);
        a[s].s[4] = (unsigned short)f2bf(f1.x);
        a[s].s[5] = (unsigned short)f2bf(f1.y);
        a[s].s[6] = (unsigned short)f2bf(f1.z);
        a[s].s[7] = (unsigned short)f2bf(f1.w);
    }
    // B fragments (8 KB table, broadcast across all blocks -> L2-resident)
    Frag b[8];
    #pragma unroll
    for (int cs = 0; cs < 8; ++cs)
        b[cs].u = *(const uint4*)(Wp + ((cs * 4 + quad) * 16 + m) * 8);

    v4f acc[4] = {};
    #pragma unroll
    for (int c = 0; c < 4; ++c) {
        acc[c] = __builtin_amdgcn_mfma_f32_16x16x32_bf16(a[0].v, b[c * 2 + 0].v, acc[c], 0, 0, 0);
        acc[c] = __builtin_amdgcn_mfma_f32_16x16x32_bf16(a[1].v, b[c * 2 + 1].v, acc[c], 0, 0, 0);
    }

    // C/D: channel = c*16 + (lane&15), node = node0 + quad*4 + r
    #pragma unroll
    for (int r = 0; r < 4; ++r) {
        int onode = node0 + quad * 4 + r;
        float di = dinv[(onode < NN) ? onode : NN - 1];
        #pragma unroll
        for (int c = 0; c < 4; ++c) {
            float v = acc[c][r] * di;
            float p = __shfl_xor(v, 1);
            if (!(lane & 1) && onode < NN) {
                unsigned pk = f2bf(v) | (f2bf(p) << 16);
                out[onode * 32 + c * 8 + (m >> 1)] = pk;
            }
        }
    }
}

// ---------------- CSR gather (bf16 rows) + fused finish ----------------
__global__ void aggregate_kernel(const int* __restrict__ row_start,
                                 const int* __restrict__ deg,
                                 const int* __restrict__ sorted_src,
                                 const uint2* __restrict__ hb,   // bf16 rows, 16 uint2/row
                                 const float* __restrict__ dinv,
                                 const float* __restrict__ b,
                                 float* __restrict__ out) {
    int tid = blockIdx.x * blockDim.x + threadIdx.x;
    int node = tid >> 4;
    int q = tid & 15;
    if (node >= NN) return;
    int e = row_start[node];
    int end = e + deg[node];
    float4 acc = bf4_to_f4(hb[node * 16 + q]);   // self-loop term
    while (e < end) {
        int take = min(end - e, 16);
        int sidx = (q < take) ? sorted_src[e + q] : 0;   // one coalesced load / 16 edges
        int j = 0;
        for (; j + 4 <= take; j += 4) {
            int s0 = __shfl(sidx, j + 0, 16);
            int s1 = __shfl(sidx, j + 1, 16);
            int s2 = __shfl(sidx, j + 2, 16);
            int s3 = __shfl(sidx, j + 3, 16);
            uint2 u0 = hb[s0 * 16 + q];
            uint2 u1 = hb[s1 * 16 + q];
            uint2 u2 = hb[s2 * 16 + q];
            uint2 u3 = hb[s3 * 16 + q];
            float4 v0 = bf4_to_f4(u0), v1 = bf4_to_f4(u1);
            float4 v2 = bf4_to_f4(u2), v3 = bf4_to_f4(u3);
            acc.x += v0.x + v1.x + v2.x + v3.x;
            acc.y += v0.y + v1.y + v2.y + v3.y;
            acc.z += v0.z + v1.z + v2.z + v3.z;
            acc.w += v0.w + v1.w + v2.w + v3.w;
        }
        for (; j < take; ++j) {
            int s0 = __shfl(sidx, j, 16);
            float4 v0 = bf4_to_f4(hb[s0 * 16 + q]);
            acc.x += v0.x; acc.y += v0.y; acc.z += v0.z; acc.w += v0.w;
        }
        e += take;
    }
    float di = dinv[node];
    float4 bb = *(const float4*)(b + q * 4);
    float4 r;
    r.x = fmaxf(fmaf(di, acc.x, bb.x), 0.f);
    r.y = fmaxf(fmaf(di, acc.y, bb.y), 0.f);
    r.z = fmaxf(fmaf(di, acc.z, bb.z), 0.f);
    r.w = fmaxf(fmaf(di, acc.w, bb.w), 0.f);
    *(float4*)(out + node * 64 + q * 4) = r;
}

// ---------------- logits = h @ Wfc + bfc ; log_softmax over 16 ----------------
__global__ void final_kernel(const float* __restrict__ h, const float* __restrict__ Wfc,
                             const float* __restrict__ bfc, float* __restrict__ out) {
    __shared__ float Ws[64][16];
    __shared__ float hs[16][68];
    int t = threadIdx.x;
    #pragma unroll
    for (int k = 0; k < 4; ++k)
        ((float*)Ws)[k * 256 + t] = Wfc[k * 256 + t];
    int node0 = blockIdx.x * 16;
    #pragma unroll
    for (int k = 0; k < 4; ++k) {
        int idx = k * 256 + t;
        int r = idx >> 6, cc = idx & 63;
        hs[r][cc] = h[(node0 + r) * 64 + cc];
    }
    __syncthreads();
    int nl = t >> 4;
    int c  = t & 15;
    float acc = bfc[c];
    #pragma unroll
    for (int k = 0; k < 64; ++k)
        acc = fmaf(hs[nl][k], Ws[k][c], acc);
    float m = acc;
    #pragma unroll
    for (int off = 8; off; off >>= 1)
        m = fmaxf(m, __shfl_xor(m, off, 16));
    float ex = __expf(acc - m);
    float s = ex;
    #pragma unroll
    for (int off = 8; off; off >>= 1)
        s += __shfl_xor(s, off, 16);
    out[(node0 + nl) * 16 + c] = acc - m - __logf(s);
}

extern "C" void kernel_launch(void* const* d_in, const int* in_sizes, int n_in,
                              void* d_out, int out_size, void* d_ws, size_t ws_size,
                              hipStream_t stream) {
    const float* x   = (const float*)d_in[0];
    const int*   ei  = (const int*)d_in[1];     // [2, E] int32
    const float* W1  = (const float*)d_in[2];
    const float* b1  = (const float*)d_in[3];
    const float* W2  = (const float*)d_in[4];
    const float* b2  = (const float*)d_in[5];
    const float* Wfc = (const float*)d_in[6];
    const float* bfc = (const float*)d_in[7];
    float* out = (float*)d_out;

    char* ws = (char*)d_ws;
    int*      deg          = (int*)(ws + 0);            // 400 KB
    float*    dinv         = (float*)(ws + 524288);     // 400 KB
    int*      row_start    = (int*)(ws + 1048576);      // 400 KB
    int*      btot         = (int*)(ws + 1572864);      // 3128 B
    int*      bucket_start = (int*)(ws + 1576960);      // 3132 B
    int*      histT        = (int*)(ws + 1581056);      // 1.6 MB (ends 3.18 MB)
    int*      baseT        = (int*)(ws + 3182592);      // 1.6 MB (ends 4.78 MB)
    int*      srt          = (int*)(ws + 4784128);      // 6.4 MB (ends 11.18 MB)
    unsigned* bufA         = (unsigned*)(ws + 11184128);// 12.8 MB bf16 hh (ends 23.98 MB)
    float*    bufB         = (float*)(ws + 23984128);   // 25.6 MB fp32 (ends 49.58 MB)
    int2*     pairs        = (int2*)(ws + 23984128);    // 12.8 MB — aliases bufB; dead
                                                        // before bufB's first write
    unsigned short* Wp1    = (unsigned short*)(ws + 49600000);  // 8 KB
    unsigned short* Wp2    = (unsigned short*)(ws + 49616384);  // 8 KB

    const int* src = ei;        // edge_index[0]
    const int* dst = ei + NE;   // edge_index[1]

    // ---- weight pack (both layers) ----
    wpack_kernel<<<2, 256, 0, stream>>>(W1, W2, Wp1, Wp2);

    // ---- CSR build (deterministic two-level counting sort; no global atomics) ----
    hist_kernel<<<NSB, 256, 0, stream>>>(dst, histT);
    colscan_kernel<<<NBUCK, 256, 0, stream>>>(histT, baseT, btot);
    bscan_kernel<<<1, 256, 0, stream>>>(btot, bucket_start);
    scatter2_kernel<<<NSB, 256, 0, stream>>>(src, dst, baseT, bucket_start, pairs);
    place_deg_kernel<<<NBUCK, 256, 0, stream>>>(bucket_start, pairs, deg, dinv, row_start, srt);

    // ---- layer 1 ----
    gemm_mfma_kernel<<<(NN + 63) / 64, 256, 0, stream>>>(x, Wp1, dinv, bufA);
    aggregate_kernel<<<(NN * 16 + 255) / 256, 256, 0, stream>>>(row_start, deg, srt, (const uint2*)bufA, dinv, b1, bufB);

    // ---- layer 2 ----
    gemm_mfma_kernel<<<(NN + 63) / 64, 256, 0, stream>>>(bufB, Wp2, dinv, bufA);
    aggregate_kernel<<<(NN * 16 + 255) / 256, 256, 0, stream>>>(row_start, deg, srt, (const uint2*)bufA, dinv, b2, bufB);

    // ---- FC + log_softmax ----
    final_kernel<<<NN / 16, 256, 0, stream>>>(bufB, Wfc, bfc, out);
}

// Round 7
// 226.193 us; speedup vs baseline: 13.2873x; 1.0691x over previous
//
#include <hip/hip_runtime.h>

#define NN 100000
#define NE 1600000
#define NPB 128                       // nodes per coarse bucket (node>>7)
#define NBUCK ((NN + NPB - 1) / NPB)  // 782
#define NSB 512                       // scatter blocks
#define ESB (NE / NSB)                // 3125 edges per scatter block
// IN_C = HID_C = 64, OUT_C = 16

typedef __bf16 v8bf __attribute__((ext_vector_type(8)));
typedef float  v4f  __attribute__((ext_vector_type(4)));

union Frag { v8bf v; uint4 u; unsigned short s[8]; };

// fp32 -> bf16 (round-to-nearest-even), returns low 16 bits
__device__ inline unsigned f2bf(float f) {
    unsigned u = __float_as_uint(f);
    return (u + 0x7fffu + ((u >> 16) & 1u)) >> 16;
}

// 4 packed bf16 (uint2) -> float4
__device__ inline float4 bf4_to_f4(uint2 u) {
    float4 r;
    r.x = __uint_as_float(u.x << 16);
    r.y = __uint_as_float(u.x & 0xffff0000u);
    r.z = __uint_as_float(u.y << 16);
    r.w = __uint_as_float(u.y & 0xffff0000u);
    return r;
}

// ---------------- S0: per-block coarse bucket histogram ----------------
__global__ void hist_kernel(const int* __restrict__ dst, int* __restrict__ histT) {
    __shared__ int lhist[NBUCK];
    int t = threadIdx.x;
    for (int i = t; i < NBUCK; i += 256) lhist[i] = 0;
    __syncthreads();
    int start = blockIdx.x * ESB, end = start + ESB;
    for (int e = start + t; e < end; e += 256)
        atomicAdd(&lhist[dst[e] >> 7], 1);
    __syncthreads();
    for (int i = t; i < NBUCK; i += 256)
        histT[i * NSB + blockIdx.x] = lhist[i];   // transposed: bucket-major
}

// ---------------- S1: per-bucket scan of 512 block counts ----------------
__global__ void colscan_kernel(const int* __restrict__ histT, int* __restrict__ baseT,
                               int* __restrict__ btot) {
    __shared__ int sd[256];
    int k = blockIdx.x, t = threadIdx.x;
    const int* col = histT + k * NSB;
    int a0 = col[2 * t], a1 = col[2 * t + 1];
    int my = a0 + a1;
    sd[t] = my;
    __syncthreads();
    #pragma unroll
    for (int off = 1; off < 256; off <<= 1) {
        int v = (t >= off) ? sd[t - off] : 0;
        __syncthreads();
        sd[t] += v;
        __syncthreads();
    }
    int excl = sd[t] - my;
    baseT[k * NSB + 2 * t]     = excl;
    baseT[k * NSB + 2 * t + 1] = excl + a0;
    if (t == 255) btot[k] = sd[255];
}

// ---------------- S2: scan bucket totals -> bucket_start[NBUCK+1] ----------------
__global__ void bscan_kernel(const int* __restrict__ btot, int* __restrict__ bucket_start) {
    __shared__ int sd[256];
    int t = threadIdx.x;
    int base = t * 4;
    int d0 = (base + 0 < NBUCK) ? btot[base + 0] : 0;
    int d1 = (base + 1 < NBUCK) ? btot[base + 1] : 0;
    int d2 = (base + 2 < NBUCK) ? btot[base + 2] : 0;
    int d3 = (base + 3 < NBUCK) ? btot[base + 3] : 0;
    int my = d0 + d1 + d2 + d3;
    sd[t] = my;
    __syncthreads();
    #pragma unroll
    for (int off = 1; off < 256; off <<= 1) {
        int v = (t >= off) ? sd[t - off] : 0;
        __syncthreads();
        sd[t] += v;
        __syncthreads();
    }
    int excl = sd[t] - my;
    if (base + 0 < NBUCK) bucket_start[base + 0] = excl;
    if (base + 1 < NBUCK) bucket_start[base + 1] = excl + d0;
    if (base + 2 < NBUCK) bucket_start[base + 2] = excl + d0 + d1;
    if (base + 3 < NBUCK) bucket_start[base + 3] = excl + d0 + d1 + d2;
    if (t == 255) bucket_start[NBUCK] = sd[255];   // == NE
}

// ---------------- S3: stable bucket scatter, packed payload ----------------
// pack = (dst & 127) << 20 | src   (src < 2^20, loc < 2^7)
__global__ void scatter2_kernel(const int* __restrict__ src, const int* __restrict__ dst,
                                const int* __restrict__ baseT,
                                const int* __restrict__ bucket_start,
                                int* __restrict__ pairs) {
    __shared__ int lcur[NBUCK];
    int t = threadIdx.x, b = blockIdx.x;
    for (int i = t; i < NBUCK; i += 256)
        lcur[i] = bucket_start[i] + baseT[i * NSB + b];
    __syncthreads();
    int start = b * ESB, end = start + ESB;
    for (int e = start + t; e < end; e += 256) {
        int d = dst[e];
        int pos = atomicAdd(&lcur[d >> 7], 1);
        pairs[pos] = ((d & 127) << 20) | src[e];
    }
}

// ---------------- S4: per-bucket deg/dinv/row_start + exact CSR placement ----
__global__ void place_deg_kernel(const int* __restrict__ bucket_start,
                                 const int* __restrict__ pairs,
                                 int* __restrict__ deg, float* __restrict__ dinv,
                                 int* __restrict__ row_start,
                                 int* __restrict__ sorted_src) {
    __shared__ int lcnt[NPB];
    __shared__ int loff[NPB];
    __shared__ int lpos[NPB];
    __shared__ int sd[NPB];
    int k = blockIdx.x, t = threadIdx.x;
    int node0 = k * NPB;
    if (t < NPB) { lcnt[t] = 0; lpos[t] = 0; }
    __syncthreads();
    int bs = bucket_start[k], be = bucket_start[k + 1];
    for (int pos = bs + t; pos < be; pos += 256)
        atomicAdd(&lcnt[pairs[pos] >> 20], 1);
    __syncthreads();
    int my = (t < NPB) ? lcnt[t] : 0;
    if (t < NPB) sd[t] = my;
    __syncthreads();
    #pragma unroll
    for (int off = 1; off < NPB; off <<= 1) {
        int v = (t < NPB && t >= off) ? sd[t - off] : 0;
        __syncthreads();
        if (t < NPB) sd[t] += v;
        __syncthreads();
    }
    if (t < NPB) {
        int excl = sd[t] - my;
        loff[t] = excl;
        int n = node0 + t;
        if (n < NN) {
            deg[n] = my;
            dinv[n] = rsqrtf((float)(my + 1));
            row_start[n] = bs + excl;
        }
    }
    __syncthreads();
    for (int pos = bs + t; pos < be; pos += 256) {
        int p = pairs[pos];
        int loc = p >> 20;
        int off = atomicAdd(&lpos[loc], 1);
        sorted_src[bs + loff[loc] + off] = p & 0xFFFFF;
    }
}

// ---------------- W pack: fp32 64x64 -> bf16 B-fragments ----------------
__global__ void wpack_kernel(const float* __restrict__ W1, const float* __restrict__ W2,
                             unsigned short* __restrict__ Wp1, unsigned short* __restrict__ Wp2) {
    const float* W = blockIdx.x ? W2 : W1;
    unsigned short* Wp = blockIdx.x ? Wp2 : Wp1;
    int t = threadIdx.x;
    for (int idx = t; idx < 4096; idx += 256) {
        int j = idx & 7;
        int n = (idx >> 3) & 15;
        int f = idx >> 7;          // 0..31
        int q = f & 3;
        int s = (f >> 2) & 1;
        int c = f >> 3;
        int k = 32 * s + 8 * q + j;
        int col = 16 * c + n;
        Wp[idx] = (unsigned short)f2bf(W[k * 64 + col]);
    }
}

// ---------------- gemm layer 1: fp32 input, bf16 output, MFMA ----------------
__global__ void gemm_mfma_f32_kernel(const float* __restrict__ in,
                                     const unsigned short* __restrict__ Wp,
                                     const float* __restrict__ dinv,
                                     unsigned* __restrict__ out) {
    int lane = threadIdx.x & 63;
    int wv = threadIdx.x >> 6;
    int node0 = blockIdx.x * 64 + wv * 16;
    int m = lane & 15, quad = lane >> 4;
    int node = node0 + m;
    int lnode = (node < NN) ? node : NN - 1;

    Frag a[2];
    const float* xr = in + lnode * 64 + quad * 8;
    #pragma unroll
    for (int s = 0; s < 2; ++s) {
        float4 f0 = *(const float4*)(xr + s * 32);
        float4 f1 = *(const float4*)(xr + s * 32 + 4);
        a[s].s[0] = (unsigned short)f2bf(f0.x);
        a[s].s[1] = (unsigned short)f2bf(f0.y);
        a[s].s[2] = (unsigned short)f2bf(f0.z);
        a[s].s[3] = (unsigned short)f2bf(f0.w);
        a[s].s[4] = (unsigned short)f2bf(f1.x);
        a[s].s[5] = (unsigned short)f2bf(f1.y);
        a[s].s[6] = (unsigned short)f2bf(f1.z);
        a[s].s[7] = (unsigned short)f2bf(f1.w);
    }
    Frag b[8];
    #pragma unroll
    for (int cs = 0; cs < 8; ++cs)
        b[cs].u = *(const uint4*)(Wp + ((cs * 4 + quad) * 16 + m) * 8);

    v4f acc[4] = {};
    #pragma unroll
    for (int c = 0; c < 4; ++c) {
        acc[c] = __builtin_amdgcn_mfma_f32_16x16x32_bf16(a[0].v, b[c * 2 + 0].v, acc[c], 0, 0, 0);
        acc[c] = __builtin_amdgcn_mfma_f32_16x16x32_bf16(a[1].v, b[c * 2 + 1].v, acc[c], 0, 0, 0);
    }
    #pragma unroll
    for (int r = 0; r < 4; ++r) {
        int onode = node0 + quad * 4 + r;
        float di = dinv[(onode < NN) ? onode : NN - 1];
        #pragma unroll
        for (int c = 0; c < 4; ++c) {
            float v = acc[c][r] * di;
            float p = __shfl_xor(v, 1);
            if (!(lane & 1) && onode < NN) {
                unsigned pk = f2bf(v) | (f2bf(p) << 16);
                out[onode * 32 + c * 8 + (m >> 1)] = pk;
            }
        }
    }
}

// ---------------- gemm layer 2: bf16 input (raw frag load), bf16 output ------
__global__ void gemm_mfma_bf16_kernel(const unsigned* __restrict__ in /* bf16 rows */,
                                      const unsigned short* __restrict__ Wp,
                                      const float* __restrict__ dinv,
                                      unsigned* __restrict__ out) {
    int lane = threadIdx.x & 63;
    int wv = threadIdx.x >> 6;
    int node0 = blockIdx.x * 64 + wv * 16;
    int m = lane & 15, quad = lane >> 4;
    int node = node0 + m;
    int lnode = (node < NN) ? node : NN - 1;

    Frag a[2];
    #pragma unroll
    for (int s = 0; s < 2; ++s)
        a[s].u = *(const uint4*)(in + lnode * 32 + s * 16 + quad * 4);

    Frag b[8];
    #pragma unroll
    for (int cs = 0; cs < 8; ++cs)
        b[cs].u = *(const uint4*)(Wp + ((cs * 4 + quad) * 16 + m) * 8);

    v4f acc[4] = {};
    #pragma unroll
    for (int c = 0; c < 4; ++c) {
        acc[c] = __builtin_amdgcn_mfma_f32_16x16x32_bf16(a[0].v, b[c * 2 + 0].v, acc[c], 0, 0, 0);
        acc[c] = __builtin_amdgcn_mfma_f32_16x16x32_bf16(a[1].v, b[c * 2 + 1].v, acc[c], 0, 0, 0);
    }
    #pragma unroll
    for (int r = 0; r < 4; ++r) {
        int onode = node0 + quad * 4 + r;
        float di = dinv[(onode < NN) ? onode : NN - 1];
        #pragma unroll
        for (int c = 0; c < 4; ++c) {
            float v = acc[c][r] * di;
            float p = __shfl_xor(v, 1);
            if (!(lane & 1) && onode < NN) {
                unsigned pk = f2bf(v) | (f2bf(p) << 16);
                out[onode * 32 + c * 8 + (m >> 1)] = pk;
            }
        }
    }
}

// ---------------- shared gather core: returns relu'd h float4 ----------------
__device__ inline float4 gather_row(const int* __restrict__ row_start,
                                    const int* __restrict__ deg,
                                    const int* __restrict__ sorted_src,
                                    const uint2* __restrict__ hb,
                                    const float* __restrict__ dinv,
                                    const float* __restrict__ b,
                                    int node, int q) {
    int e = row_start[node];
    int end = e + deg[node];
    float4 acc = bf4_to_f4(hb[node * 16 + q]);   // self-loop term
    while (e < end) {
        int take = min(end - e, 16);
        int sidx = (q < take) ? sorted_src[e + q] : 0;
        int j = 0;
        for (; j + 4 <= take; j += 4) {
            int s0 = __shfl(sidx, j + 0, 16);
            int s1 = __shfl(sidx, j + 1, 16);
            int s2 = __shfl(sidx, j + 2, 16);
            int s3 = __shfl(sidx, j + 3, 16);
            uint2 u0 = hb[s0 * 16 + q];
            uint2 u1 = hb[s1 * 16 + q];
            uint2 u2 = hb[s2 * 16 + q];
            uint2 u3 = hb[s3 * 16 + q];
            float4 v0 = bf4_to_f4(u0), v1 = bf4_to_f4(u1);
            float4 v2 = bf4_to_f4(u2), v3 = bf4_to_f4(u3);
            acc.x += v0.x + v1.x + v2.x + v3.x;
            acc.y += v0.y + v1.y + v2.y + v3.y;
            acc.z += v0.z + v1.z + v2.z + v3.z;
            acc.w += v0.w + v1.w + v2.w + v3.w;
        }
        for (; j < take; ++j) {
            int s0 = __shfl(sidx, j, 16);
            float4 v0 = bf4_to_f4(hb[s0 * 16 + q]);
            acc.x += v0.x; acc.y += v0.y; acc.z += v0.z; acc.w += v0.w;
        }
        e += take;
    }
    float di = dinv[node];
    float4 bb = *(const float4*)(b + q * 4);
    float4 r;
    r.x = fmaxf(fmaf(di, acc.x, bb.x), 0.f);
    r.y = fmaxf(fmaf(di, acc.y, bb.y), 0.f);
    r.z = fmaxf(fmaf(di, acc.z, bb.z), 0.f);
    r.w = fmaxf(fmaf(di, acc.w, bb.w), 0.f);
    return r;
}

// ---------------- layer-1 aggregate: writes bf16 rows ----------------
__global__ void aggregate1_kernel(const int* __restrict__ row_start,
                                  const int* __restrict__ deg,
                                  const int* __restrict__ sorted_src,
                                  const uint2* __restrict__ hb,
                                  const float* __restrict__ dinv,
                                  const float* __restrict__ b,
                                  unsigned* __restrict__ out /* bf16 rows */) {
    int tid = blockIdx.x * blockDim.x + threadIdx.x;
    int node = tid >> 4;
    int q = tid & 15;
    float4 r = gather_row(row_start, deg, sorted_src, hb, dinv, b, node, q);
    uint2 pk;
    pk.x = f2bf(r.x) | (f2bf(r.y) << 16);
    pk.y = f2bf(r.z) | (f2bf(r.w) << 16);
    *(uint2*)(out + node * 32 + q * 2) = pk;
}

// ---------------- layer-2 aggregate fused with FC + log_softmax --------------
__global__ void aggregate2_final_kernel(const int* __restrict__ row_start,
                                        const int* __restrict__ deg,
                                        const int* __restrict__ sorted_src,
                                        const uint2* __restrict__ hb,
                                        const float* __restrict__ dinv,
                                        const float* __restrict__ b,
                                        const float* __restrict__ Wfc,
                                        const float* __restrict__ bfc,
                                        float* __restrict__ out) {
    __shared__ float Ws[64][16];   // 4 KB
    __shared__ float hs[16][68];   // padded
    int t = threadIdx.x;
    #pragma unroll
    for (int k = 0; k < 4; ++k)
        ((float*)Ws)[k * 256 + t] = Wfc[k * 256 + t];

    int node = blockIdx.x * 16 + (t >> 4);
    int q = t & 15;
    float4 r = gather_row(row_start, deg, sorted_src, hb, dinv, b, node, q);
    hs[t >> 4][q * 4 + 0] = r.x;
    hs[t >> 4][q * 4 + 1] = r.y;
    hs[t >> 4][q * 4 + 2] = r.z;
    hs[t >> 4][q * 4 + 3] = r.w;
    __syncthreads();

    int nl = t >> 4;
    int c  = t & 15;
    float acc = bfc[c];
    #pragma unroll
    for (int k = 0; k < 64; ++k)
        acc = fmaf(hs[nl][k], Ws[k][c], acc);
    float m = acc;
    #pragma unroll
    for (int off = 8; off; off >>= 1)
        m = fmaxf(m, __shfl_xor(m, off, 16));
    float ex = __expf(acc - m);
    float s = ex;
    #pragma unroll
    for (int off = 8; off; off >>= 1)
        s += __shfl_xor(s, off, 16);
    out[blockIdx.x * 256 + t] = acc - m - __logf(s);
}

extern "C" void kernel_launch(void* const* d_in, const int* in_sizes, int n_in,
                              void* d_out, int out_size, void* d_ws, size_t ws_size,
                              hipStream_t stream) {
    const float* x   = (const float*)d_in[0];
    const int*   ei  = (const int*)d_in[1];     // [2, E] int32
    const float* W1  = (const float*)d_in[2];
    const float* b1  = (const float*)d_in[3];
    const float* W2  = (const float*)d_in[4];
    const float* b2  = (const float*)d_in[5];
    const float* Wfc = (const float*)d_in[6];
    const float* bfc = (const float*)d_in[7];
    float* out = (float*)d_out;

    char* ws = (char*)d_ws;
    int*      deg          = (int*)(ws + 0);            // 400 KB
    float*    dinv         = (float*)(ws + 524288);     // 400 KB
    int*      row_start    = (int*)(ws + 1048576);      // 400 KB
    int*      btot         = (int*)(ws + 1572864);      // 3128 B
    int*      bucket_start = (int*)(ws + 1576960);      // 3132 B
    int*      histT        = (int*)(ws + 1581056);      // 1.6 MB (ends 3.18 MB)
    int*      baseT        = (int*)(ws + 3182592);      // 1.6 MB (ends 4.78 MB)
    int*      srt          = (int*)(ws + 4784128);      // 6.4 MB (ends 11.18 MB)
    unsigned* bufA         = (unsigned*)(ws + 11184128);// 12.8 MB bf16 rows (ends 23.98 MB)
    unsigned* bufC         = (unsigned*)(ws + 23984128);// 12.8 MB bf16 rows (ends 36.78 MB)
    int*      pairs        = (int*)(ws + 36784128);     // 6.4 MB (ends 43.18 MB)
    unsigned short* Wp1    = (unsigned short*)(ws + 43200000);  // 8 KB
    unsigned short* Wp2    = (unsigned short*)(ws + 43216384);  // 8 KB

    const int* src = ei;        // edge_index[0]
    const int* dst = ei + NE;   // edge_index[1]

    // ---- weight pack (both layers) ----
    wpack_kernel<<<2, 256, 0, stream>>>(W1, W2, Wp1, Wp2);

    // ---- CSR build (deterministic two-level counting sort; no global atomics) ----
    hist_kernel<<<NSB, 256, 0, stream>>>(dst, histT);
    colscan_kernel<<<NBUCK, 256, 0, stream>>>(histT, baseT, btot);
    bscan_kernel<<<1, 256, 0, stream>>>(btot, bucket_start);
    scatter2_kernel<<<NSB, 256, 0, stream>>>(src, dst, baseT, bucket_start, pairs);
    place_deg_kernel<<<NBUCK, 256, 0, stream>>>(bucket_start, pairs, deg, dinv, row_start, srt);

    // ---- layer 1 ----
    gemm_mfma_f32_kernel<<<(NN + 63) / 64, 256, 0, stream>>>(x, Wp1, dinv, bufA);
    aggregate1_kernel<<<NN * 16 / 256, 256, 0, stream>>>(row_start, deg, srt, (const uint2*)bufA, dinv, b1, bufC);

    // ---- layer 2 ----
    gemm_mfma_bf16_kernel<<<(NN + 63) / 64, 256, 0, stream>>>(bufC, Wp2, dinv, bufA);
    aggregate2_final_kernel<<<NN * 16 / 256, 256, 0, stream>>>(row_start, deg, srt, (const uint2*)bufA, dinv, b2, Wfc, bfc, out);
}

// Round 8
// 218.388 us; speedup vs baseline: 13.7621x; 1.0357x over previous
//
#include <hip/hip_runtime.h>

#define NN 100000
#define NE 1600000
#define NPB 128                       // nodes per coarse bucket (node>>7)
#define NBUCK ((NN + NPB - 1) / NPB)  // 782
#define NSB 512                       // scatter blocks
#define ESB (NE / NSB)                // 3125 edges per scatter block
#define PCAP 3072                     // LDS staging cap in place_deg (bucket avg ~2046)
// IN_C = HID_C = 64, OUT_C = 16

typedef __bf16 v8bf __attribute__((ext_vector_type(8)));
typedef float  v4f  __attribute__((ext_vector_type(4)));

union Frag { v8bf v; uint4 u; unsigned short s[8]; };

// fp32 -> bf16 (round-to-nearest-even), returns low 16 bits
__device__ inline unsigned f2bf(float f) {
    unsigned u = __float_as_uint(f);
    return (u + 0x7fffu + ((u >> 16) & 1u)) >> 16;
}

// 4 packed bf16 (uint2) -> float4
__device__ inline float4 bf4_to_f4(uint2 u) {
    float4 r;
    r.x = __uint_as_float(u.x << 16);
    r.y = __uint_as_float(u.x & 0xffff0000u);
    r.z = __uint_as_float(u.y << 16);
    r.w = __uint_as_float(u.y & 0xffff0000u);
    return r;
}

// ---------------- S0: per-block coarse bucket histogram ----------------
__global__ void hist_kernel(const int* __restrict__ dst, int* __restrict__ histT) {
    __shared__ int lhist[NBUCK];
    int t = threadIdx.x;
    for (int i = t; i < NBUCK; i += 256) lhist[i] = 0;
    __syncthreads();
    int start = blockIdx.x * ESB, end = start + ESB;
    for (int e = start + t; e < end; e += 256)
        atomicAdd(&lhist[dst[e] >> 7], 1);
    __syncthreads();
    for (int i = t; i < NBUCK; i += 256)
        histT[i * NSB + blockIdx.x] = lhist[i];   // transposed: bucket-major
}

// ---------------- S1: per-bucket scan of 512 block counts ----------------
__global__ void colscan_kernel(const int* __restrict__ histT, int* __restrict__ baseT,
                               int* __restrict__ btot) {
    __shared__ int sd[256];
    int k = blockIdx.x, t = threadIdx.x;
    const int* col = histT + k * NSB;
    int a0 = col[2 * t], a1 = col[2 * t + 1];
    int my = a0 + a1;
    sd[t] = my;
    __syncthreads();
    #pragma unroll
    for (int off = 1; off < 256; off <<= 1) {
        int v = (t >= off) ? sd[t - off] : 0;
        __syncthreads();
        sd[t] += v;
        __syncthreads();
    }
    int excl = sd[t] - my;
    baseT[k * NSB + 2 * t]     = excl;
    baseT[k * NSB + 2 * t + 1] = excl + a0;
    if (t == 255) btot[k] = sd[255];
}

// ---------------- S2: scan bucket totals -> bucket_start[NBUCK+1] ----------------
__global__ void bscan_kernel(const int* __restrict__ btot, int* __restrict__ bucket_start) {
    __shared__ int sd[256];
    int t = threadIdx.x;
    int base = t * 4;
    int d0 = (base + 0 < NBUCK) ? btot[base + 0] : 0;
    int d1 = (base + 1 < NBUCK) ? btot[base + 1] : 0;
    int d2 = (base + 2 < NBUCK) ? btot[base + 2] : 0;
    int d3 = (base + 3 < NBUCK) ? btot[base + 3] : 0;
    int my = d0 + d1 + d2 + d3;
    sd[t] = my;
    __syncthreads();
    #pragma unroll
    for (int off = 1; off < 256; off <<= 1) {
        int v = (t >= off) ? sd[t - off] : 0;
        __syncthreads();
        sd[t] += v;
        __syncthreads();
    }
    int excl = sd[t] - my;
    if (base + 0 < NBUCK) bucket_start[base + 0] = excl;
    if (base + 1 < NBUCK) bucket_start[base + 1] = excl + d0;
    if (base + 2 < NBUCK) bucket_start[base + 2] = excl + d0 + d1;
    if (base + 3 < NBUCK) bucket_start[base + 3] = excl + d0 + d1 + d2;
    if (t == 255) bucket_start[NBUCK] = sd[255];   // == NE
}

// ---------------- S3: stable bucket scatter, packed payload ----------------
// pack = (dst & 127) << 20 | src   (src < 2^20, loc < 2^7)
__global__ void scatter2_kernel(const int* __restrict__ src, const int* __restrict__ dst,
                                const int* __restrict__ baseT,
                                const int* __restrict__ bucket_start,
                                int* __restrict__ pairs) {
    __shared__ int lcur[NBUCK];
    int t = threadIdx.x, b = blockIdx.x;
    for (int i = t; i < NBUCK; i += 256)
        lcur[i] = bucket_start[i] + baseT[i * NSB + b];
    __syncthreads();
    int start = b * ESB, end = start + ESB;
    for (int e = start + t; e < end; e += 256) {
        int d = dst[e];
        int pos = atomicAdd(&lcur[d >> 7], 1);
        pairs[pos] = ((d & 127) << 20) | src[e];
    }
}

// ---------------- S4: per-bucket deg/dinv/row_start + CSR placement ----------
// Single global read of pairs: staged in LDS (fallback to global past PCAP).
__global__ void place_deg_kernel(const int* __restrict__ bucket_start,
                                 const int* __restrict__ pairs,
                                 int* __restrict__ deg, float* __restrict__ dinv,
                                 int* __restrict__ row_start,
                                 int* __restrict__ sorted_src) {
    __shared__ int lp[PCAP];
    __shared__ int lcnt[NPB];
    __shared__ int loff[NPB];
    __shared__ int lpos[NPB];
    __shared__ int sd[NPB];
    int k = blockIdx.x, t = threadIdx.x;
    int node0 = k * NPB;
    if (t < NPB) { lcnt[t] = 0; lpos[t] = 0; }
    __syncthreads();
    int bs = bucket_start[k], be = bucket_start[k + 1];
    int n = be - bs;
    for (int pos = t; pos < n; pos += 256) {
        int p = pairs[bs + pos];
        if (pos < PCAP) lp[pos] = p;
        atomicAdd(&lcnt[p >> 20], 1);
    }
    __syncthreads();
    int my = (t < NPB) ? lcnt[t] : 0;
    if (t < NPB) sd[t] = my;
    __syncthreads();
    #pragma unroll
    for (int off = 1; off < NPB; off <<= 1) {
        int v = (t < NPB && t >= off) ? sd[t - off] : 0;
        __syncthreads();
        if (t < NPB) sd[t] += v;
        __syncthreads();
    }
    if (t < NPB) {
        int excl = sd[t] - my;
        loff[t] = excl;
        int nd = node0 + t;
        if (nd < NN) {
            deg[nd] = my;
            dinv[nd] = rsqrtf((float)(my + 1));
            row_start[nd] = bs + excl;
        }
    }
    __syncthreads();
    for (int pos = t; pos < n; pos += 256) {
        int p = (pos < PCAP) ? lp[pos] : pairs[bs + pos];
        int loc = p >> 20;
        int off = atomicAdd(&lpos[loc], 1);
        sorted_src[bs + loff[loc] + off] = p & 0xFFFFF;
    }
}

// ---------------- W pack: fp32 64x64 -> bf16 B-fragments ----------------
__global__ void wpack_kernel(const float* __restrict__ W1, const float* __restrict__ W2,
                             unsigned short* __restrict__ Wp1, unsigned short* __restrict__ Wp2) {
    const float* W = blockIdx.x ? W2 : W1;
    unsigned short* Wp = blockIdx.x ? Wp2 : Wp1;
    int t = threadIdx.x;
    for (int idx = t; idx < 4096; idx += 256) {
        int j = idx & 7;
        int n = (idx >> 3) & 15;
        int f = idx >> 7;          // 0..31
        int q = f & 3;
        int s = (f >> 2) & 1;
        int c = f >> 3;
        int k = 32 * s + 8 * q + j;
        int col = 16 * c + n;
        Wp[idx] = (unsigned short)f2bf(W[k * 64 + col]);
    }
}

// ---------------- gemm layer 1: fp32 input, bf16 output, MFMA ----------------
__global__ void gemm_mfma_f32_kernel(const float* __restrict__ in,
                                     const unsigned short* __restrict__ Wp,
                                     const float* __restrict__ dinv,
                                     unsigned* __restrict__ out) {
    int lane = threadIdx.x & 63;
    int wv = threadIdx.x >> 6;
    int node0 = blockIdx.x * 64 + wv * 16;
    int m = lane & 15, quad = lane >> 4;
    int node = node0 + m;
    int lnode = (node < NN) ? node : NN - 1;

    Frag a[2];
    const float* xr = in + lnode * 64 + quad * 8;
    #pragma unroll
    for (int s = 0; s < 2; ++s) {
        float4 f0 = *(const float4*)(xr + s * 32);
        float4 f1 = *(const float4*)(xr + s * 32 + 4);
        a[s].s[0] = (unsigned short)f2bf(f0.x);
        a[s].s[1] = (unsigned short)f2bf(f0.y);
        a[s].s[2] = (unsigned short)f2bf(f0.z);
        a[s].s[3] = (unsigned short)f2bf(f0.w);
        a[s].s[4] = (unsigned short)f2bf(f1.x);
        a[s].s[5] = (unsigned short)f2bf(f1.y);
        a[s].s[6] = (unsigned short)f2bf(f1.z);
        a[s].s[7] = (unsigned short)f2bf(f1.w);
    }
    Frag b[8];
    #pragma unroll
    for (int cs = 0; cs < 8; ++cs)
        b[cs].u = *(const uint4*)(Wp + ((cs * 4 + quad) * 16 + m) * 8);

    v4f acc[4] = {};
    #pragma unroll
    for (int c = 0; c < 4; ++c) {
        acc[c] = __builtin_amdgcn_mfma_f32_16x16x32_bf16(a[0].v, b[c * 2 + 0].v, acc[c], 0, 0, 0);
        acc[c] = __builtin_amdgcn_mfma_f32_16x16x32_bf16(a[1].v, b[c * 2 + 1].v, acc[c], 0, 0, 0);
    }
    #pragma unroll
    for (int r = 0; r < 4; ++r) {
        int onode = node0 + quad * 4 + r;
        float di = dinv[(onode < NN) ? onode : NN - 1];
        #pragma unroll
        for (int c = 0; c < 4; ++c) {
            float v = acc[c][r] * di;
            float p = __shfl_xor(v, 1);
            if (!(lane & 1) && onode < NN) {
                unsigned pk = f2bf(v) | (f2bf(p) << 16);
                out[onode * 32 + c * 8 + (m >> 1)] = pk;
            }
        }
    }
}

// ---------------- shared gather core: returns relu'd h float4 ----------------
__device__ inline float4 gather_row(const int* __restrict__ row_start,
                                    const int* __restrict__ deg,
                                    const int* __restrict__ sorted_src,
                                    const uint2* __restrict__ hb,
                                    const float* __restrict__ dinv,
                                    const float* __restrict__ b,
                                    int node, int q) {
    int e = row_start[node];
    int end = e + deg[node];
    float4 acc = bf4_to_f4(hb[node * 16 + q]);   // self-loop term
    while (e < end) {
        int take = min(end - e, 16);
        int sidx = (q < take) ? sorted_src[e + q] : 0;
        int j = 0;
        for (; j + 8 <= take; j += 8) {
            int s0 = __shfl(sidx, j + 0, 16);
            int s1 = __shfl(sidx, j + 1, 16);
            int s2 = __shfl(sidx, j + 2, 16);
            int s3 = __shfl(sidx, j + 3, 16);
            int s4 = __shfl(sidx, j + 4, 16);
            int s5 = __shfl(sidx, j + 5, 16);
            int s6 = __shfl(sidx, j + 6, 16);
            int s7 = __shfl(sidx, j + 7, 16);
            uint2 u0 = hb[s0 * 16 + q];
            uint2 u1 = hb[s1 * 16 + q];
            uint2 u2 = hb[s2 * 16 + q];
            uint2 u3 = hb[s3 * 16 + q];
            uint2 u4 = hb[s4 * 16 + q];
            uint2 u5 = hb[s5 * 16 + q];
            uint2 u6 = hb[s6 * 16 + q];
            uint2 u7 = hb[s7 * 16 + q];
            float4 v0 = bf4_to_f4(u0), v1 = bf4_to_f4(u1);
            float4 v2 = bf4_to_f4(u2), v3 = bf4_to_f4(u3);
            float4 v4 = bf4_to_f4(u4), v5 = bf4_to_f4(u5);
            float4 v6 = bf4_to_f4(u6), v7 = bf4_to_f4(u7);
            acc.x += (v0.x + v1.x) + (v2.x + v3.x) + (v4.x + v5.x) + (v6.x + v7.x);
            acc.y += (v0.y + v1.y) + (v2.y + v3.y) + (v4.y + v5.y) + (v6.y + v7.y);
            acc.z += (v0.z + v1.z) + (v2.z + v3.z) + (v4.z + v5.z) + (v6.z + v7.z);
            acc.w += (v0.w + v1.w) + (v2.w + v3.w) + (v4.w + v5.w) + (v6.w + v7.w);
        }
        for (; j + 4 <= take; j += 4) {
            int s0 = __shfl(sidx, j + 0, 16);
            int s1 = __shfl(sidx, j + 1, 16);
            int s2 = __shfl(sidx, j + 2, 16);
            int s3 = __shfl(sidx, j + 3, 16);
            uint2 u0 = hb[s0 * 16 + q];
            uint2 u1 = hb[s1 * 16 + q];
            uint2 u2 = hb[s2 * 16 + q];
            uint2 u3 = hb[s3 * 16 + q];
            float4 v0 = bf4_to_f4(u0), v1 = bf4_to_f4(u1);
            float4 v2 = bf4_to_f4(u2), v3 = bf4_to_f4(u3);
            acc.x += (v0.x + v1.x) + (v2.x + v3.x);
            acc.y += (v0.y + v1.y) + (v2.y + v3.y);
            acc.z += (v0.z + v1.z) + (v2.z + v3.z);
            acc.w += (v0.w + v1.w) + (v2.w + v3.w);
        }
        for (; j < take; ++j) {
            int s0 = __shfl(sidx, j, 16);
            float4 v0 = bf4_to_f4(hb[s0 * 16 + q]);
            acc.x += v0.x; acc.y += v0.y; acc.z += v0.z; acc.w += v0.w;
        }
        e += take;
    }
    float di = dinv[node];
    float4 bb = *(const float4*)(b + q * 4);
    float4 r;
    r.x = fmaxf(fmaf(di, acc.x, bb.x), 0.f);
    r.y = fmaxf(fmaf(di, acc.y, bb.y), 0.f);
    r.z = fmaxf(fmaf(di, acc.z, bb.z), 0.f);
    r.w = fmaxf(fmaf(di, acc.w, bb.w), 0.f);
    return r;
}

// ---------------- fused: layer-1 aggregate -> LDS -> layer-2 gemm (MFMA) -----
// Block = 256 threads = 64 nodes. Gather h1 rows, stage bf16 in LDS
// (72-short row stride: <=2-way banks), each wave MFMAs its 16-node tile,
// writes hh2 = (h1 @ W2) * dinv as bf16 rows.
__global__ void agg1_gemm2_kernel(const int* __restrict__ row_start,
                                  const int* __restrict__ deg,
                                  const int* __restrict__ sorted_src,
                                  const uint2* __restrict__ hb,    // hh1 bf16 rows
                                  const float* __restrict__ dinv,
                                  const float* __restrict__ b1,
                                  const unsigned short* __restrict__ Wp2,
                                  unsigned* __restrict__ out /* hh2 bf16 rows */) {
    __shared__ unsigned short hsl[64][72];   // 9216 B
    int t = threadIdx.x;
    int lane = t & 63, wv = t >> 6;
    int node0 = blockIdx.x * 64;
    int q = lane & 15;

    // gather phase: 4 rounds x 4 concurrent nodes per wave
    #pragma unroll
    for (int r4 = 0; r4 < 4; ++r4) {
        int nl = wv * 16 + r4 * 4 + (lane >> 4);
        int node = node0 + nl;
        int cn = (node < NN) ? node : NN - 1;
        float4 r = gather_row(row_start, deg, sorted_src, hb, dinv, b1, cn, q);
        uint2 pk;
        pk.x = f2bf(r.x) | (f2bf(r.y) << 16);
        pk.y = f2bf(r.z) | (f2bf(r.w) << 16);
        *(uint2*)&hsl[nl][q * 4] = pk;
    }
    __syncthreads();

    // MFMA phase: wave wv computes nodes node0 + wv*16 .. +15
    int m = lane & 15, quad = lane >> 4;
    Frag b[8];
    #pragma unroll
    for (int cs = 0; cs < 8; ++cs)
        b[cs].u = *(const uint4*)(Wp2 + ((cs * 4 + quad) * 16 + m) * 8);
    Frag a[2];
    #pragma unroll
    for (int s = 0; s < 2; ++s)
        a[s].u = *(const uint4*)&hsl[wv * 16 + m][s * 32 + quad * 8];

    v4f acc[4] = {};
    #pragma unroll
    for (int c = 0; c < 4; ++c) {
        acc[c] = __builtin_amdgcn_mfma_f32_16x16x32_bf16(a[0].v, b[c * 2 + 0].v, acc[c], 0, 0, 0);
        acc[c] = __builtin_amdgcn_mfma_f32_16x16x32_bf16(a[1].v, b[c * 2 + 1].v, acc[c], 0, 0, 0);
    }
    #pragma unroll
    for (int r = 0; r < 4; ++r) {
        int onode = node0 + wv * 16 + quad * 4 + r;
        float di = dinv[(onode < NN) ? onode : NN - 1];
        #pragma unroll
        for (int c = 0; c < 4; ++c) {
            float v = acc[c][r] * di;
            float p = __shfl_xor(v, 1);
            if (!(lane & 1) && onode < NN) {
                unsigned pk = f2bf(v) | (f2bf(p) << 16);
                out[onode * 32 + c * 8 + (m >> 1)] = pk;
            }
        }
    }
}

// ---------------- layer-2 aggregate fused with FC + log_softmax --------------
__global__ void aggregate2_final_kernel(const int* __restrict__ row_start,
                                        const int* __restrict__ deg,
                                        const int* __restrict__ sorted_src,
                                        const uint2* __restrict__ hb,
                                        const float* __restrict__ dinv,
                                        const float* __restrict__ b,
                                        const float* __restrict__ Wfc,
                                        const float* __restrict__ bfc,
                                        float* __restrict__ out) {
    __shared__ float Ws[64][16];   // 4 KB
    __shared__ float hs[16][68];   // padded
    int t = threadIdx.x;
    #pragma unroll
    for (int k = 0; k < 4; ++k)
        ((float*)Ws)[k * 256 + t] = Wfc[k * 256 + t];

    int node = blockIdx.x * 16 + (t >> 4);
    int q = t & 15;
    float4 r = gather_row(row_start, deg, sorted_src, hb, dinv, b, node, q);
    hs[t >> 4][q * 4 + 0] = r.x;
    hs[t >> 4][q * 4 + 1] = r.y;
    hs[t >> 4][q * 4 + 2] = r.z;
    hs[t >> 4][q * 4 + 3] = r.w;
    __syncthreads();

    int nl = t >> 4;
    int c  = t & 15;
    float acc = bfc[c];
    #pragma unroll
    for (int k = 0; k < 64; ++k)
        acc = fmaf(hs[nl][k], Ws[k][c], acc);
    float m = acc;
    #pragma unroll
    for (int off = 8; off; off >>= 1)
        m = fmaxf(m, __shfl_xor(m, off, 16));
    float ex = __expf(acc - m);
    float s = ex;
    #pragma unroll
    for (int off = 8; off; off >>= 1)
        s += __shfl_xor(s, off, 16);
    out[blockIdx.x * 256 + t] = acc - m - __logf(s);
}

extern "C" void kernel_launch(void* const* d_in, const int* in_sizes, int n_in,
                              void* d_out, int out_size, void* d_ws, size_t ws_size,
                              hipStream_t stream) {
    const float* x   = (const float*)d_in[0];
    const int*   ei  = (const int*)d_in[1];     // [2, E] int32
    const float* W1  = (const float*)d_in[2];
    const float* b1  = (const float*)d_in[3];
    const float* W2  = (const float*)d_in[4];
    const float* b2  = (const float*)d_in[5];
    const float* Wfc = (const float*)d_in[6];
    const float* bfc = (const float*)d_in[7];
    float* out = (float*)d_out;

    char* ws = (char*)d_ws;
    int*      deg          = (int*)(ws + 0);            // 400 KB
    float*    dinv         = (float*)(ws + 524288);     // 400 KB
    int*      row_start    = (int*)(ws + 1048576);      // 400 KB
    int*      btot         = (int*)(ws + 1572864);      // 3128 B
    int*      bucket_start = (int*)(ws + 1576960);      // 3132 B
    int*      histT        = (int*)(ws + 1581056);      // 1.6 MB (ends 3.18 MB)
    int*      baseT        = (int*)(ws + 3182592);      // 1.6 MB (ends 4.78 MB)
    int*      srt          = (int*)(ws + 4784128);      // 6.4 MB (ends 11.18 MB)
    unsigned* bufA         = (unsigned*)(ws + 11184128);// 12.8 MB bf16 hh1 (ends 23.98 MB)
    unsigned* bufC         = (unsigned*)(ws + 23984128);// 12.8 MB bf16 hh2 (ends 36.78 MB)
    int*      pairs        = (int*)(ws + 36784128);     // 6.4 MB (ends 43.18 MB)
    unsigned short* Wp1    = (unsigned short*)(ws + 43200000);  // 8 KB
    unsigned short* Wp2    = (unsigned short*)(ws + 43216384);  // 8 KB

    const int* src = ei;        // edge_index[0]
    const int* dst = ei + NE;   // edge_index[1]

    // ---- weight pack (both layers) ----
    wpack_kernel<<<2, 256, 0, stream>>>(W1, W2, Wp1, Wp2);

    // ---- CSR build (deterministic two-level counting sort; no global atomics) ----
    hist_kernel<<<NSB, 256, 0, stream>>>(dst, histT);
    colscan_kernel<<<NBUCK, 256, 0, stream>>>(histT, baseT, btot);
    bscan_kernel<<<1, 256, 0, stream>>>(btot, bucket_start);
    scatter2_kernel<<<NSB, 256, 0, stream>>>(src, dst, baseT, bucket_start, pairs);
    place_deg_kernel<<<NBUCK, 256, 0, stream>>>(bucket_start, pairs, deg, dinv, row_start, srt);

    // ---- layer 1 gemm ----
    gemm_mfma_f32_kernel<<<(NN + 63) / 64, 256, 0, stream>>>(x, Wp1, dinv, bufA);

    // ---- layer 1 aggregate + layer 2 gemm (fused) ----
    agg1_gemm2_kernel<<<(NN + 63) / 64, 256, 0, stream>>>(row_start, deg, srt,
        (const uint2*)bufA, dinv, b1, Wp2, bufC);

    // ---- layer 2 aggregate + FC + log_softmax (fused) ----
    aggregate2_final_kernel<<<NN * 16 / 256, 256, 0, stream>>>(row_start, deg, srt,
        (const uint2*)bufC, dinv, b2, Wfc, bfc, out);
}